// Round 1
// 655.183 us; speedup vs baseline: 2.8783x; 2.8783x over previous
//
#include <hip/hip_runtime.h>

// FlashAttentionWrapper: B=2, S=2048, D=2048, NH=32, HD=64, NKV=8, NREP=4,
// causal, RoPE theta=1e4. Input dtype (bf16/f32) detected at runtime.
// New-path workspace (60MB+1KB):
//   [flag 4B pad 1KB][kvbuf 4096x1024 8MB][abuf 4096x2048 16MB]
//   [hbuf 16MB][wqb 8MB][wkvb 4MB][wob 8MB]
// Q-projection result lives in d_out (dead before O-proj overwrites it).
// Fallback path (ws < 60MB): previous direct-load kernels, 24MB+1KB.

#define S_LEN 2048
#define D_MODEL 2048
#define NHEAD 32
#define HEAD_DIM 64
#define NKVH 8
#define M_ROWS 4096   // B*S

typedef __attribute__((ext_vector_type(4))) float f32x4;
typedef __attribute__((ext_vector_type(8))) short bf16x8;

#define MFMA16(a, b, c) __builtin_amdgcn_mfma_f32_16x16x32_bf16((a), (b), (c), 0, 0, 0)

// async global->LDS, 16B per lane; LDS dest is wave-uniform base + lane*16
#define GLOAD_LDS16(g, l)                                                     \
    __builtin_amdgcn_global_load_lds(                                         \
        (const __attribute__((address_space(1))) void*)(g),                   \
        (__attribute__((address_space(3))) void*)(l), 16, 0, 0)

static __device__ __forceinline__ unsigned short f2bf(float f) {
    union { float f; unsigned int i; } v; v.f = f;
    unsigned int x = v.i;
    unsigned int r = (x + 0x7fffu + ((x >> 16) & 1u)) >> 16;  // RNE
    return (unsigned short)r;
}

// ---------------------------------------------------------------------------
// Dtype detection (unchanged): f32 data read as uint16 shows impossible bf16
// exponents at even indices.
// ---------------------------------------------------------------------------
__global__ __launch_bounds__(256) void detect_dtype(const unsigned short* __restrict__ h,
                                                    int* __restrict__ flag) {
    __shared__ int cnt;
    if (threadIdx.x == 0) cnt = 0;
    __syncthreads();
    const unsigned short v = h[2 * threadIdx.x];
    const int e = (v >> 7) & 0xFF;
    if (e >= 0x8D) atomicAdd(&cnt, 1);
    __syncthreads();
    if (threadIdx.x == 0) *flag = (cnt >= 8) ? 1 : 0;
}

static __device__ __forceinline__ bf16x8 load_frag(bool f32p, const void* p, size_t off) {
    if (f32p) {
        const float* fp = (const float*)p + off;
        f32x4 x = *reinterpret_cast<const f32x4*>(fp);
        f32x4 y = *reinterpret_cast<const f32x4*>(fp + 4);
        bf16x8 r;
        r[0] = (short)f2bf(x[0]); r[1] = (short)f2bf(x[1]);
        r[2] = (short)f2bf(x[2]); r[3] = (short)f2bf(x[3]);
        r[4] = (short)f2bf(y[0]); r[5] = (short)f2bf(y[1]);
        r[6] = (short)f2bf(y[2]); r[7] = (short)f2bf(y[3]);
        return r;
    }
    return *reinterpret_cast<const bf16x8*>((const unsigned short*)p + off);
}

// ---------------------------------------------------------------------------
// One-time f32->bf16 conversion (or bf16 copy). n8 = element count / 8.
// ---------------------------------------------------------------------------
__global__ __launch_bounds__(256) void cvt_bf16(const void* __restrict__ src,
                                                unsigned short* __restrict__ dst,
                                                int n8, const int* __restrict__ flag) {
    const bool f32p = (*flag != 0);
    int i = blockIdx.x * 256 + threadIdx.x;
    const int stride = gridDim.x * 256;
    for (; i < n8; i += stride) {
        bf16x8 v = load_frag(f32p, src, (size_t)i * 8);
        *reinterpret_cast<bf16x8*>(dst + (size_t)i * 8) = v;
    }
}

// ---------------------------------------------------------------------------
// LDS-staged GEMM (m97 structure): C[M,N] = A[M,2048] @ W[N,2048]^T, all bf16.
// 128x128 tile, BK=32, 4 waves in 2x2 (each 64x64), global_load_lds width=16,
// 16 MFMA + 8 ds_read_b128 per K-step, 2-barrier loop.
// rope: 0=none, 1=all cols, 2=cols<512 only (fused K|V GEMM).
// finalout!=0 && *flag!=0 -> f32 output, else bf16.
// ---------------------------------------------------------------------------
__global__ __launch_bounds__(256) void gemm_bt_lds(const unsigned short* __restrict__ A,
                                                   const unsigned short* __restrict__ W,
                                                   void* __restrict__ Cp, int N,
                                                   const int* __restrict__ flag,
                                                   int rope, int finalout) {
    __shared__ unsigned short lds_a[128 * 32];   // 8KB
    __shared__ unsigned short lds_b[128 * 32];   // 8KB

    const int wave = threadIdx.x >> 6;
    const int lane = threadIdx.x & 63;
    const int l16  = lane & 15;
    const int quad = lane >> 4;
    const int wm   = wave >> 1;       // 0..1: m-quadrant
    const int wn   = wave & 1;        // 0..1: n-quadrant

    const int m0 = blockIdx.x * 128;
    const int n0 = blockIdx.y * 128;

    // staging: chunk c = wave*2+i covers tile rows [16c,16c+16), 1KB per wave-op
    const int srow = lane >> 2;        // 0..15
    const int scol = (lane & 3) * 8;   // 0,8,16,24 (elements)
    const unsigned short* ag[2];
    const unsigned short* wg[2];
#pragma unroll
    for (int i = 0; i < 2; ++i) {
        const int c = wave * 2 + i;
        ag[i] = A + (size_t)(m0 + c * 16 + srow) * D_MODEL + scol;
        wg[i] = W + (size_t)(n0 + c * 16 + srow) * D_MODEL + scol;
    }

    f32x4 acc[4][4];
#pragma unroll
    for (int i = 0; i < 4; ++i)
#pragma unroll
        for (int j = 0; j < 4; ++j) acc[i][j] = (f32x4){0.f, 0.f, 0.f, 0.f};

    for (int k0 = 0; k0 < D_MODEL; k0 += 32) {
#pragma unroll
        for (int i = 0; i < 2; ++i) {
            const int c = wave * 2 + i;
            GLOAD_LDS16(ag[i] + k0, &lds_a[c * 512]);
            GLOAD_LDS16(wg[i] + k0, &lds_b[c * 512]);
        }
        __syncthreads();   // compiler emits vmcnt(0) drain before s_barrier

        bf16x8 af[4], bfm[4];
#pragma unroll
        for (int t = 0; t < 4; ++t) {
            af[t]  = *reinterpret_cast<const bf16x8*>(&lds_a[(wm * 64 + t * 16 + l16) * 32 + quad * 8]);
            bfm[t] = *reinterpret_cast<const bf16x8*>(&lds_b[(wn * 64 + t * 16 + l16) * 32 + quad * 8]);
        }
#pragma unroll
        for (int mt = 0; mt < 4; ++mt)
#pragma unroll
            for (int nt = 0; nt < 4; ++nt)
                acc[mt][nt] = MFMA16(af[mt], bfm[nt], acc[mt][nt]);
        __syncthreads();   // all waves done reading before next stage overwrites
    }

    const bool isf32 = (*flag != 0);
    const bool of32  = isf32 && (finalout != 0);
    const bool do_rope = (rope == 1) || (rope == 2 && (n0 + wn * 64) < (NKVH * HEAD_DIM));
    const int ncol0 = n0 + wn * 64;   // wave's 64-col span is head-aligned (HD=64)

#pragma unroll
    for (int mt = 0; mt < 4; ++mt) {
#pragma unroll
        for (int r = 0; r < 4; ++r) {
            const int m = m0 + wm * 64 + mt * 16 + quad * 4 + r;
            float vals[4];
#pragma unroll
            for (int nt = 0; nt < 4; ++nt) vals[nt] = acc[mt][nt][r];
            float outv[4];
            if (do_rope) {
                const float sf = (float)(m & (S_LEN - 1));
#pragma unroll
                for (int nt = 0; nt < 4; ++nt) {
                    const int d = nt * 16 + l16;             // col mod 64
                    // inv_freq = 10000^(-(d&31)/32) = 2^(-(d&31)*log2(1e4)/32)
                    const float inv = exp2f(-(float)(d & 31) * 0.4152410118609203f);
                    const float th = sf * inv;
                    float sn, cs;
                    sincosf(th, &sn, &cs);
                    const float part = vals[nt ^ 2];
                    const float rot = (nt < 2) ? -part : part;  // d<32: -x2 ; d>=32: +x1
                    outv[nt] = vals[nt] * cs + rot * sn;
                }
            } else {
#pragma unroll
                for (int nt = 0; nt < 4; ++nt) outv[nt] = vals[nt];
            }
            const size_t crow = (size_t)m * N + ncol0;
            if (of32) {
                float* cp = (float*)Cp + crow;
#pragma unroll
                for (int nt = 0; nt < 4; ++nt) cp[nt * 16 + l16] = outv[nt];
            } else {
                unsigned short* cp = (unsigned short*)Cp + crow;
#pragma unroll
                for (int nt = 0; nt < 4; ++nt) cp[nt * 16 + l16] = f2bf(outv[nt]);
            }
        }
    }
}

// ---------------------------------------------------------------------------
// Legacy direct-load GEMM (fallback path only; handles f32/bf16 inputs).
// ---------------------------------------------------------------------------
__global__ __launch_bounds__(256) void gemm_bt(const void* __restrict__ Ap,
                                               const void* __restrict__ Wp,
                                               void* __restrict__ Cp, int N,
                                               const int* __restrict__ flag,
                                               int a_input, int rope, int finalout) {
    const bool isf32 = (*flag != 0);
    const bool af32 = isf32 && (a_input != 0);
    const bool wf32 = isf32;
    const bool of32 = isf32 && (finalout != 0);

    const int wave = threadIdx.x >> 6;
    const int lane = threadIdx.x & 63;
    const int l16  = lane & 15;
    const int quad = lane >> 4;
    const int m0 = blockIdx.x * 64 + wave * 16;
    const int n0 = blockIdx.y * 64;

    f32x4 acc[4];
#pragma unroll
    for (int i = 0; i < 4; ++i) acc[i] = (f32x4){0.f, 0.f, 0.f, 0.f};

    const size_t aoff = (size_t)(m0 + l16) * D_MODEL + quad * 8;
    size_t woff[4];
#pragma unroll
    for (int nt = 0; nt < 4; ++nt)
        woff[nt] = (size_t)(n0 + nt * 16 + l16) * D_MODEL + quad * 8;

    for (int k0 = 0; k0 < D_MODEL; k0 += 32) {
        bf16x8 a = load_frag(af32, Ap, aoff + k0);
#pragma unroll
        for (int nt = 0; nt < 4; ++nt) {
            bf16x8 b = load_frag(wf32, Wp, woff[nt] + k0);
            acc[nt] = MFMA16(a, b, acc[nt]);
        }
    }

#pragma unroll
    for (int r = 0; r < 4; ++r) {
        const int m = m0 + quad * 4 + r;
        float vals[4];
#pragma unroll
        for (int nt = 0; nt < 4; ++nt) vals[nt] = acc[nt][r];
        float outv[4];
        if (rope) {
            const float sf = (float)(m & (S_LEN - 1));
#pragma unroll
            for (int nt = 0; nt < 4; ++nt) {
                const int d = nt * 16 + l16;
                const float inv = exp2f(-(float)(d & 31) * 0.4152410118609203f);
                const float th = sf * inv;
                float sn, cs;
                sincosf(th, &sn, &cs);
                const float part = vals[nt ^ 2];
                const float rot = (nt < 2) ? -part : part;
                outv[nt] = vals[nt] * cs + rot * sn;
            }
        } else {
#pragma unroll
            for (int nt = 0; nt < 4; ++nt) outv[nt] = vals[nt];
        }
        const size_t crow = (size_t)m * N + n0;
        if (of32) {
            float* cp = (float*)Cp + crow;
#pragma unroll
            for (int nt = 0; nt < 4; ++nt) cp[nt * 16 + l16] = outv[nt];
        } else {
            unsigned short* cp = (unsigned short*)Cp + crow;
#pragma unroll
            for (int nt = 0; nt < 4; ++nt) cp[nt * 16 + l16] = f2bf(outv[nt]);
        }
    }
}

// ---------------------------------------------------------------------------
// Flash attention, causal, GQA. kvs = row stride (elements) of K/V buffers
// (512 = separate buffers, 1024 = fused KV buffer).
// ---------------------------------------------------------------------------
__global__ __launch_bounds__(256) void attn_kernel(const unsigned short* __restrict__ Q,
                                                   const unsigned short* __restrict__ Kb,
                                                   const unsigned short* __restrict__ Vb,
                                                   unsigned short* __restrict__ O, int kvs) {
    __shared__ unsigned short lp[4][16][32];   // per-wave P tile (16 q x 32 k)

    const int wave = threadIdx.x >> 6;
    const int lane = threadIdx.x & 63;
    const int l16  = lane & 15;
    const int quad = lane >> 4;

    const int bid = blockIdx.x;
    const int qb  = bid & 31;
    const int h   = (bid >> 5) & 31;
    const int b   = bid >> 10;
    const int kvh = h >> 2;
    const int q0  = qb * 64 + wave * 16;

    const unsigned short* qbase = Q + (size_t)b * S_LEN * D_MODEL + h * HEAD_DIM;
    const unsigned short* kbase = Kb + (size_t)b * S_LEN * kvs + kvh * HEAD_DIM;
    const unsigned short* vbase = Vb + (size_t)b * S_LEN * kvs + kvh * HEAD_DIM;

    bf16x8 aq0 = *reinterpret_cast<const bf16x8*>(qbase + (size_t)(q0 + l16) * D_MODEL + quad * 8);
    bf16x8 aq1 = *reinterpret_cast<const bf16x8*>(qbase + (size_t)(q0 + l16) * D_MODEL + 32 + quad * 8);

    f32x4 o[4];
#pragma unroll
    for (int i = 0; i < 4; ++i) o[i] = (f32x4){0.f, 0.f, 0.f, 0.f};
    float mrow[4], lrow[4];
#pragma unroll
    for (int r = 0; r < 4; ++r) { mrow[r] = -3.0e38f; lrow[r] = 0.f; }

    const int kv_hi = qb * 64 + 64;
    for (int k0 = 0; k0 < kv_hi; k0 += 32) {
        f32x4 sc[2];
#pragma unroll
        for (int t = 0; t < 2; ++t) {
            const unsigned short* krow = kbase + (size_t)(k0 + t * 16 + l16) * kvs;
            bf16x8 b0 = *reinterpret_cast<const bf16x8*>(krow + quad * 8);
            bf16x8 b1 = *reinterpret_cast<const bf16x8*>(krow + 32 + quad * 8);
            f32x4 c = (f32x4){0.f, 0.f, 0.f, 0.f};
            c = MFMA16(aq0, b0, c);
            c = MFMA16(aq1, b1, c);
            sc[t] = c;
        }

        float alpha[4], p0v[4], p1v[4];
#pragma unroll
        for (int r = 0; r < 4; ++r) {
            const int qi = q0 + quad * 4 + r;
            float s0 = sc[0][r] * 0.125f;
            float s1 = sc[1][r] * 0.125f;
            if (k0 + l16 > qi)       s0 = -1.0e30f;
            if (k0 + 16 + l16 > qi)  s1 = -1.0e30f;
            float mt = fmaxf(s0, s1);
#pragma unroll
            for (int off = 1; off < 16; off <<= 1) mt = fmaxf(mt, __shfl_xor(mt, off, 64));
            const float mn = fmaxf(mrow[r], mt);
            const float al = __expf(mrow[r] - mn);
            const float p0 = __expf(s0 - mn);
            const float p1 = __expf(s1 - mn);
            float rs = p0 + p1;
#pragma unroll
            for (int off = 1; off < 16; off <<= 1) rs += __shfl_xor(rs, off, 64);
            lrow[r] = lrow[r] * al + rs;
            mrow[r] = mn;
            alpha[r] = al;
            p0v[r] = p0; p1v[r] = p1;
        }
#pragma unroll
        for (int nt = 0; nt < 4; ++nt)
#pragma unroll
            for (int r = 0; r < 4; ++r) o[nt][r] *= alpha[r];

        __syncthreads();
#pragma unroll
        for (int r = 0; r < 4; ++r) {
            lp[wave][quad * 4 + r][l16]      = f2bf(p0v[r]);
            lp[wave][quad * 4 + r][16 + l16] = f2bf(p1v[r]);
        }
        __syncthreads();
        bf16x8 ap = *reinterpret_cast<const bf16x8*>(&lp[wave][l16][quad * 8]);

#pragma unroll
        for (int nt = 0; nt < 4; ++nt) {
            const unsigned short* vcol = vbase + nt * 16 + l16 + (size_t)(k0 + quad * 8) * kvs;
            bf16x8 bv;
#pragma unroll
            for (int j = 0; j < 8; ++j) bv[j] = (short)vcol[(size_t)j * kvs];
            o[nt] = MFMA16(ap, bv, o[nt]);
        }
    }

    unsigned short* obase = O + (size_t)b * S_LEN * D_MODEL + h * HEAD_DIM;
#pragma unroll
    for (int r = 0; r < 4; ++r) {
        const float inv_l = 1.0f / lrow[r];
        unsigned short* orow = obase + (size_t)(q0 + quad * 4 + r) * D_MODEL;
#pragma unroll
        for (int nt = 0; nt < 4; ++nt)
            orow[nt * 16 + l16] = f2bf(o[nt][r] * inv_l);
    }
}

extern "C" void kernel_launch(void* const* d_in, const int* in_sizes, int n_in,
                              void* d_out, int out_size, void* d_ws, size_t ws_size,
                              hipStream_t stream) {
    const void* hidden = d_in[0];
    const void* Wq = d_in[1];
    const void* Wk = d_in[2];
    const void* Wv = d_in[3];
    const void* Wo = d_in[4];
    // d_in[5] = attention_mask: pure causal -1e9 -> implemented directly.

    char* ws = (char*)d_ws;
    int* flag = (int*)ws;
    dim3 blk(256);

    detect_dtype<<<1, blk, 0, stream>>>((const unsigned short*)hidden, flag);

    // New path needs: kv 8MB + abuf 16MB + hbuf 16MB + wq 8MB + wkv 4MB + wo 8MB
    const size_t NEED = 1024 + 2ull * ((size_t)4096 * 1024 + (size_t)4096 * 2048 +
                                       (size_t)4096 * 2048 + (size_t)2048 * 2048 +
                                       (size_t)1024 * 2048 + (size_t)2048 * 2048);
    if (ws_size >= NEED) {
        unsigned short* kvbuf = (unsigned short*)(ws + 1024);      // [4096,1024]: K cols 0-511, V cols 512-1023
        unsigned short* abuf  = kvbuf + (size_t)4096 * 1024;       // [4096,2048]
        unsigned short* hbuf  = abuf + (size_t)4096 * 2048;        // hidden bf16
        unsigned short* wqb   = hbuf + (size_t)4096 * 2048;        // [2048,2048]
        unsigned short* wkvb  = wqb + (size_t)2048 * 2048;         // [1024,2048]: Wk rows 0-511, Wv rows 512-1023
        unsigned short* wob   = wkvb + (size_t)1024 * 2048;        // [2048,2048]
        unsigned short* qbuf  = (unsigned short*)d_out;            // Q bf16 lives in d_out

        cvt_bf16<<<dim3(2048), blk, 0, stream>>>(hidden, hbuf, M_ROWS * D_MODEL / 8, flag);
        cvt_bf16<<<dim3(1024), blk, 0, stream>>>(Wq, wqb, 2048 * 2048 / 8, flag);
        cvt_bf16<<<dim3(256),  blk, 0, stream>>>(Wk, wkvb, 512 * 2048 / 8, flag);
        cvt_bf16<<<dim3(256),  blk, 0, stream>>>(Wv, wkvb + (size_t)512 * 2048, 512 * 2048 / 8, flag);
        cvt_bf16<<<dim3(1024), blk, 0, stream>>>(Wo, wob, 2048 * 2048 / 8, flag);

        gemm_bt_lds<<<dim3(32, 16), blk, 0, stream>>>(hbuf, wqb, qbuf, 2048, flag, 1, 0);
        gemm_bt_lds<<<dim3(32, 8),  blk, 0, stream>>>(hbuf, wkvb, kvbuf, 1024, flag, 2, 0);
        attn_kernel<<<dim3(2 * NHEAD * (S_LEN / 64)), blk, 0, stream>>>(qbuf, kvbuf, kvbuf + 512, abuf, 1024);
        gemm_bt_lds<<<dim3(32, 16), blk, 0, stream>>>(abuf, wob, d_out, 2048, flag, 0, 1);
    } else {
        // legacy 24MB path
        unsigned short* kbuf = (unsigned short*)(ws + 1024);
        unsigned short* vbuf = (unsigned short*)(ws + 1024 + (4u << 20));
        unsigned short* abuf = (unsigned short*)(ws + 1024 + (8u << 20));
        unsigned short* qbuf = (unsigned short*)d_out;
        gemm_bt<<<dim3(M_ROWS / 64, D_MODEL / 64), blk, 0, stream>>>(hidden, Wq, qbuf, D_MODEL, flag, 1, 1, 0);
        gemm_bt<<<dim3(M_ROWS / 64, (NKVH * HEAD_DIM) / 64), blk, 0, stream>>>(hidden, Wk, kbuf, NKVH * HEAD_DIM, flag, 1, 1, 0);
        gemm_bt<<<dim3(M_ROWS / 64, (NKVH * HEAD_DIM) / 64), blk, 0, stream>>>(hidden, Wv, vbuf, NKVH * HEAD_DIM, flag, 1, 0, 0);
        attn_kernel<<<dim3(2 * NHEAD * (S_LEN / 64)), blk, 0, stream>>>(qbuf, kbuf, vbuf, abuf, 512);
        gemm_bt<<<dim3(M_ROWS / 64, D_MODEL / 64), blk, 0, stream>>>(abuf, Wo, d_out, D_MODEL, flag, 0, 0, 1);
    }
}

// Round 2
// 629.062 us; speedup vs baseline: 2.9978x; 1.0415x over previous
//
#include <hip/hip_runtime.h>

// FlashAttentionWrapper: B=2, S=2048, D=2048, NH=32, HD=64, NKV=8, NREP=4,
// causal, RoPE theta=1e4. Input dtype (bf16/f32) detected at runtime.
// New-path workspace (64MB+1KB):
//   [flag 4B pad 1KB][kvbuf 4096x1024 8MB][abuf 4096x2048 16MB]
//   [hbuf 16MB][wqb 8MB][wkvb 4MB][wob 8MB][vtbuf 2x512x2048 4MB]
// Q-projection result lives in d_out (dead before O-proj overwrites it).
// Fallback path (ws < 64MB+1KB): original direct-load kernels, 24MB+1KB.

#define S_LEN 2048
#define D_MODEL 2048
#define NHEAD 32
#define HEAD_DIM 64
#define NKVH 8
#define M_ROWS 4096   // B*S
#define KVW (NKVH * HEAD_DIM)   // 512

typedef __attribute__((ext_vector_type(4))) float f32x4;
typedef __attribute__((ext_vector_type(8))) short bf16x8;

#define MFMA16(a, b, c) __builtin_amdgcn_mfma_f32_16x16x32_bf16((a), (b), (c), 0, 0, 0)

// async global->LDS, 16B per lane; LDS dest is wave-uniform base + lane*16
#define GLOAD_LDS16(g, l)                                                     \
    __builtin_amdgcn_global_load_lds(                                         \
        (const __attribute__((address_space(1))) void*)(g),                   \
        (__attribute__((address_space(3))) void*)(l), 16, 0, 0)

static __device__ __forceinline__ unsigned short f2bf(float f) {
    union { float f; unsigned int i; } v; v.f = f;
    unsigned int x = v.i;
    unsigned int r = (x + 0x7fffu + ((x >> 16) & 1u)) >> 16;  // RNE
    return (unsigned short)r;
}

// ---------------------------------------------------------------------------
// Dtype detection: f32 data read as uint16 shows impossible bf16 exponents at
// even indices.
// ---------------------------------------------------------------------------
__global__ __launch_bounds__(256) void detect_dtype(const unsigned short* __restrict__ h,
                                                    int* __restrict__ flag) {
    __shared__ int cnt;
    if (threadIdx.x == 0) cnt = 0;
    __syncthreads();
    const unsigned short v = h[2 * threadIdx.x];
    const int e = (v >> 7) & 0xFF;
    if (e >= 0x8D) atomicAdd(&cnt, 1);
    __syncthreads();
    if (threadIdx.x == 0) *flag = (cnt >= 8) ? 1 : 0;
}

static __device__ __forceinline__ bf16x8 load_frag(bool f32p, const void* p, size_t off) {
    if (f32p) {
        const float* fp = (const float*)p + off;
        f32x4 x = *reinterpret_cast<const f32x4*>(fp);
        f32x4 y = *reinterpret_cast<const f32x4*>(fp + 4);
        bf16x8 r;
        r[0] = (short)f2bf(x[0]); r[1] = (short)f2bf(x[1]);
        r[2] = (short)f2bf(x[2]); r[3] = (short)f2bf(x[3]);
        r[4] = (short)f2bf(y[0]); r[5] = (short)f2bf(y[1]);
        r[6] = (short)f2bf(y[2]); r[7] = (short)f2bf(y[3]);
        return r;
    }
    return *reinterpret_cast<const bf16x8*>((const unsigned short*)p + off);
}

// ---------------------------------------------------------------------------
// One-time f32->bf16 conversion (or bf16 copy). n8 = element count / 8.
// ---------------------------------------------------------------------------
__global__ __launch_bounds__(256) void cvt_bf16(const void* __restrict__ src,
                                                unsigned short* __restrict__ dst,
                                                int n8, const int* __restrict__ flag) {
    const bool f32p = (*flag != 0);
    int i = blockIdx.x * 256 + threadIdx.x;
    const int stride = gridDim.x * 256;
    for (; i < n8; i += stride) {
        bf16x8 v = load_frag(f32p, src, (size_t)i * 8);
        *reinterpret_cast<bf16x8*>(dst + (size_t)i * 8) = v;
    }
}

// ---------------------------------------------------------------------------
// LDS-staged GEMM (m97 structure): C[M,N] = A[M,2048] @ W[N,2048]^T, all bf16.
// 128x128 tile, BK=32, 4 waves 2x2, global_load_lds width=16.
// rope: 0=none, 1=all cols, 2=cols<512 only (fused K|V GEMM).
// ---------------------------------------------------------------------------
__global__ __launch_bounds__(256) void gemm_bt_lds(const unsigned short* __restrict__ A,
                                                   const unsigned short* __restrict__ W,
                                                   void* __restrict__ Cp, int N,
                                                   const int* __restrict__ flag,
                                                   int rope, int finalout) {
    __shared__ unsigned short lds_a[128 * 32];   // 8KB
    __shared__ unsigned short lds_b[128 * 32];   // 8KB

    const int wave = threadIdx.x >> 6;
    const int lane = threadIdx.x & 63;
    const int l16  = lane & 15;
    const int quad = lane >> 4;
    const int wm   = wave >> 1;
    const int wn   = wave & 1;

    const int m0 = blockIdx.x * 128;
    const int n0 = blockIdx.y * 128;

    const int srow = lane >> 2;
    const int scol = (lane & 3) * 8;
    const unsigned short* ag[2];
    const unsigned short* wg[2];
#pragma unroll
    for (int i = 0; i < 2; ++i) {
        const int c = wave * 2 + i;
        ag[i] = A + (size_t)(m0 + c * 16 + srow) * D_MODEL + scol;
        wg[i] = W + (size_t)(n0 + c * 16 + srow) * D_MODEL + scol;
    }

    f32x4 acc[4][4];
#pragma unroll
    for (int i = 0; i < 4; ++i)
#pragma unroll
        for (int j = 0; j < 4; ++j) acc[i][j] = (f32x4){0.f, 0.f, 0.f, 0.f};

    for (int k0 = 0; k0 < D_MODEL; k0 += 32) {
#pragma unroll
        for (int i = 0; i < 2; ++i) {
            const int c = wave * 2 + i;
            GLOAD_LDS16(ag[i] + k0, &lds_a[c * 512]);
            GLOAD_LDS16(wg[i] + k0, &lds_b[c * 512]);
        }
        __syncthreads();

        bf16x8 af[4], bfm[4];
#pragma unroll
        for (int t = 0; t < 4; ++t) {
            af[t]  = *reinterpret_cast<const bf16x8*>(&lds_a[(wm * 64 + t * 16 + l16) * 32 + quad * 8]);
            bfm[t] = *reinterpret_cast<const bf16x8*>(&lds_b[(wn * 64 + t * 16 + l16) * 32 + quad * 8]);
        }
#pragma unroll
        for (int mt = 0; mt < 4; ++mt)
#pragma unroll
            for (int nt = 0; nt < 4; ++nt)
                acc[mt][nt] = MFMA16(af[mt], bfm[nt], acc[mt][nt]);
        __syncthreads();
    }

    const bool isf32 = (*flag != 0);
    const bool of32  = isf32 && (finalout != 0);
    const bool do_rope = (rope == 1) || (rope == 2 && (n0 + wn * 64) < KVW);
    const int ncol0 = n0 + wn * 64;

#pragma unroll
    for (int mt = 0; mt < 4; ++mt) {
#pragma unroll
        for (int r = 0; r < 4; ++r) {
            const int m = m0 + wm * 64 + mt * 16 + quad * 4 + r;
            float vals[4];
#pragma unroll
            for (int nt = 0; nt < 4; ++nt) vals[nt] = acc[mt][nt][r];
            float outv[4];
            if (do_rope) {
                const float sf = (float)(m & (S_LEN - 1));
#pragma unroll
                for (int nt = 0; nt < 4; ++nt) {
                    const int d = nt * 16 + l16;
                    const float inv = exp2f(-(float)(d & 31) * 0.4152410118609203f);
                    const float th = sf * inv;
                    float sn, cs;
                    sincosf(th, &sn, &cs);
                    const float part = vals[nt ^ 2];
                    const float rot = (nt < 2) ? -part : part;
                    outv[nt] = vals[nt] * cs + rot * sn;
                }
            } else {
#pragma unroll
                for (int nt = 0; nt < 4; ++nt) outv[nt] = vals[nt];
            }
            const size_t crow = (size_t)m * N + ncol0;
            if (of32) {
                float* cp = (float*)Cp + crow;
#pragma unroll
                for (int nt = 0; nt < 4; ++nt) cp[nt * 16 + l16] = outv[nt];
            } else {
                unsigned short* cp = (unsigned short*)Cp + crow;
#pragma unroll
                for (int nt = 0; nt < 4; ++nt) cp[nt * 16 + l16] = f2bf(outv[nt]);
            }
        }
    }
}

// ---------------------------------------------------------------------------
// V transpose: Vsrc = kvbuf V-half [B*S rows, stride 1024] cols 0..511
//   -> Vt[b][c][s] ([B][512][S]).  64x64 LDS tiles, fully coalesced.
// ---------------------------------------------------------------------------
__global__ __launch_bounds__(256) void transpose_v(const unsigned short* __restrict__ Vsrc,
                                                   unsigned short* __restrict__ Vt) {
    __shared__ unsigned short t[64][72];
    const int bid = blockIdx.x;
    const int ct = bid & 7;            // 8 col-tiles (512/64)
    const int st = (bid >> 3) & 31;    // 32 s-tiles (2048/64)
    const int b  = bid >> 8;
    const unsigned short* src = Vsrc + ((size_t)b * S_LEN + st * 64) * 1024 + ct * 64;
    unsigned short* dst = Vt + ((size_t)b * KVW + ct * 64) * S_LEN + st * 64;
    const int r0 = threadIdx.x >> 3;
    const int c0 = (threadIdx.x & 7) * 8;
#pragma unroll
    for (int h = 0; h < 2; ++h) {
        bf16x8 v = *reinterpret_cast<const bf16x8*>(src + (size_t)(r0 + h * 32) * 1024 + c0);
        *reinterpret_cast<bf16x8*>(&t[r0 + h * 32][c0]) = v;
    }
    __syncthreads();
#pragma unroll
    for (int h = 0; h < 2; ++h) {
        const int cr = r0 + h * 32;
        bf16x8 v;
#pragma unroll
        for (int j = 0; j < 8; ++j) v[j] = (short)t[c0 + j][cr];
        *reinterpret_cast<bf16x8*>(dst + (size_t)cr * S_LEN + c0) = v;
    }
}

// ---------------------------------------------------------------------------
// Flash attention v2: causal, GQA. 4 independent waves/block, 32 q-rows/wave,
// 64-key tiles, per-wave causal bound, no block barriers (P tile is per-wave
// LDS; same-wave DS ops are in-order). K read row-major (16B frags), V read
// from the transposed Vt buffer (16B frags).
// ---------------------------------------------------------------------------
__global__ __launch_bounds__(256) void attn_kernel2(const unsigned short* __restrict__ Q,
                                                    const unsigned short* __restrict__ Kb,
                                                    const unsigned short* __restrict__ Vt,
                                                    unsigned short* __restrict__ O, int kvs) {
    __shared__ unsigned short lp[4][32][72];   // per-wave P (32 q x 64 k), padded

    const int wave = threadIdx.x >> 6;
    const int lane = threadIdx.x & 63;
    const int l16  = lane & 15;
    const int quad = lane >> 4;

    const int bid = blockIdx.x;
    const int qt  = (S_LEN / 128 - 1) - (bid & (S_LEN / 128 - 1));  // heavy tiles first
    const int h   = (bid >> 4) & (NHEAD - 1);
    const int b   = bid >> 9;
    const int kvh = h >> 2;
    const int q0w = qt * 128 + wave * 32;

    const unsigned short* qbase  = Q + (size_t)b * S_LEN * D_MODEL + h * HEAD_DIM;
    const unsigned short* kbase  = Kb + (size_t)b * S_LEN * kvs + kvh * HEAD_DIM;
    const unsigned short* vtbase = Vt + ((size_t)b * KVW + kvh * HEAD_DIM) * S_LEN;

    // Q fragments: aq[m][kh], rows q0w + m*16 + l16, k = kh*32 + quad*8 + j
    bf16x8 aq[2][2];
#pragma unroll
    for (int m = 0; m < 2; ++m)
#pragma unroll
        for (int kh = 0; kh < 2; ++kh)
            aq[m][kh] = *reinterpret_cast<const bf16x8*>(
                qbase + (size_t)(q0w + m * 16 + l16) * D_MODEL + kh * 32 + quad * 8);

    f32x4 o[2][4];
#pragma unroll
    for (int m = 0; m < 2; ++m)
#pragma unroll
        for (int i = 0; i < 4; ++i) o[m][i] = (f32x4){0.f, 0.f, 0.f, 0.f};
    float mrow[2][4], lrow[2][4];
#pragma unroll
    for (int m = 0; m < 2; ++m)
#pragma unroll
        for (int r = 0; r < 4; ++r) { mrow[m][r] = -3.0e38f; lrow[m][r] = 0.f; }

    const int kv_hi = q0w + 32;   // per-wave causal bound
    for (int k0 = 0; k0 < kv_hi; k0 += 64) {
        // ---- scores: sc[m][t] = Q(m-tile) @ K(t-chunk)^T ----
        f32x4 sc[2][4];
#pragma unroll
        for (int t = 0; t < 4; ++t) {
            const unsigned short* krow = kbase + (size_t)(k0 + t * 16 + l16) * kvs;
            bf16x8 b0 = *reinterpret_cast<const bf16x8*>(krow + quad * 8);
            bf16x8 b1 = *reinterpret_cast<const bf16x8*>(krow + 32 + quad * 8);
#pragma unroll
            for (int m = 0; m < 2; ++m) {
                f32x4 c = (f32x4){0.f, 0.f, 0.f, 0.f};
                c = MFMA16(aq[m][0], b0, c);
                c = MFMA16(aq[m][1], b1, c);
                sc[m][t] = c;
            }
        }

        const bool full = (k0 + 63 <= q0w);   // wave-uniform: tile entirely below diagonal
        float alpha[2][4];
#pragma unroll
        for (int m = 0; m < 2; ++m) {
#pragma unroll
            for (int r = 0; r < 4; ++r) {
                const int qi = q0w + m * 16 + quad * 4 + r;
                float s[4];
#pragma unroll
                for (int t = 0; t < 4; ++t) s[t] = sc[m][t][r] * 0.125f;
                if (!full) {
#pragma unroll
                    for (int t = 0; t < 4; ++t)
                        if (k0 + t * 16 + l16 > qi) s[t] = -1.0e30f;
                }
                float mt = fmaxf(fmaxf(s[0], s[1]), fmaxf(s[2], s[3]));
#pragma unroll
                for (int off = 1; off < 16; off <<= 1) mt = fmaxf(mt, __shfl_xor(mt, off, 64));
                const float mn = fmaxf(mrow[m][r], mt);
                const float al = __expf(mrow[m][r] - mn);
                float p[4], rs = 0.f;
#pragma unroll
                for (int t = 0; t < 4; ++t) { p[t] = __expf(s[t] - mn); rs += p[t]; }
#pragma unroll
                for (int off = 1; off < 16; off <<= 1) rs += __shfl_xor(rs, off, 64);
                lrow[m][r] = lrow[m][r] * al + rs;
                mrow[m][r] = mn;
                alpha[m][r] = al;
#pragma unroll
                for (int t = 0; t < 4; ++t)
                    lp[wave][m * 16 + quad * 4 + r][t * 16 + l16] = f2bf(p[t]);
            }
        }
#pragma unroll
        for (int m = 0; m < 2; ++m)
#pragma unroll
            for (int nt = 0; nt < 4; ++nt)
#pragma unroll
                for (int r = 0; r < 4; ++r) o[m][nt][r] *= alpha[m][r];

        // ds_write -> ds_read: same-wave LDS, DS pipe is in-order; fence stops
        // compiler reordering only (no barrier needed — lp slice is per-wave).
        asm volatile("" ::: "memory");

        bf16x8 ap[2][2];
#pragma unroll
        for (int m = 0; m < 2; ++m)
#pragma unroll
            for (int kh = 0; kh < 2; ++kh)
                ap[m][kh] = *reinterpret_cast<const bf16x8*>(&lp[wave][m * 16 + l16][kh * 32 + quad * 8]);

        // ---- PV: o[m][nt] += P @ V, V fragments contiguous from Vt ----
#pragma unroll
        for (int nt = 0; nt < 4; ++nt) {
            const unsigned short* vrow = vtbase + (size_t)(nt * 16 + l16) * S_LEN + k0 + quad * 8;
            bf16x8 bv0 = *reinterpret_cast<const bf16x8*>(vrow);
            bf16x8 bv1 = *reinterpret_cast<const bf16x8*>(vrow + 32);
#pragma unroll
            for (int m = 0; m < 2; ++m) {
                o[m][nt] = MFMA16(ap[m][0], bv0, o[m][nt]);
                o[m][nt] = MFMA16(ap[m][1], bv1, o[m][nt]);
            }
        }
    }

    unsigned short* obase = O + (size_t)b * S_LEN * D_MODEL + h * HEAD_DIM;
#pragma unroll
    for (int m = 0; m < 2; ++m)
#pragma unroll
        for (int r = 0; r < 4; ++r) {
            const float inv_l = 1.0f / lrow[m][r];
            unsigned short* orow = obase + (size_t)(q0w + m * 16 + quad * 4 + r) * D_MODEL;
#pragma unroll
            for (int nt = 0; nt < 4; ++nt)
                orow[nt * 16 + l16] = f2bf(o[m][nt][r] * inv_l);
        }
}

// ---------------------------------------------------------------------------
// Legacy direct-load GEMM + attention (fallback path only).
// ---------------------------------------------------------------------------
__global__ __launch_bounds__(256) void gemm_bt(const void* __restrict__ Ap,
                                               const void* __restrict__ Wp,
                                               void* __restrict__ Cp, int N,
                                               const int* __restrict__ flag,
                                               int a_input, int rope, int finalout) {
    const bool isf32 = (*flag != 0);
    const bool af32 = isf32 && (a_input != 0);
    const bool wf32 = isf32;
    const bool of32 = isf32 && (finalout != 0);

    const int wave = threadIdx.x >> 6;
    const int lane = threadIdx.x & 63;
    const int l16  = lane & 15;
    const int quad = lane >> 4;
    const int m0 = blockIdx.x * 64 + wave * 16;
    const int n0 = blockIdx.y * 64;

    f32x4 acc[4];
#pragma unroll
    for (int i = 0; i < 4; ++i) acc[i] = (f32x4){0.f, 0.f, 0.f, 0.f};

    const size_t aoff = (size_t)(m0 + l16) * D_MODEL + quad * 8;
    size_t woff[4];
#pragma unroll
    for (int nt = 0; nt < 4; ++nt)
        woff[nt] = (size_t)(n0 + nt * 16 + l16) * D_MODEL + quad * 8;

    for (int k0 = 0; k0 < D_MODEL; k0 += 32) {
        bf16x8 a = load_frag(af32, Ap, aoff + k0);
#pragma unroll
        for (int nt = 0; nt < 4; ++nt) {
            bf16x8 b = load_frag(wf32, Wp, woff[nt] + k0);
            acc[nt] = MFMA16(a, b, acc[nt]);
        }
    }

#pragma unroll
    for (int r = 0; r < 4; ++r) {
        const int m = m0 + quad * 4 + r;
        float vals[4];
#pragma unroll
        for (int nt = 0; nt < 4; ++nt) vals[nt] = acc[nt][r];
        float outv[4];
        if (rope) {
            const float sf = (float)(m & (S_LEN - 1));
#pragma unroll
            for (int nt = 0; nt < 4; ++nt) {
                const int d = nt * 16 + l16;
                const float inv = exp2f(-(float)(d & 31) * 0.4152410118609203f);
                const float th = sf * inv;
                float sn, cs;
                sincosf(th, &sn, &cs);
                const float part = vals[nt ^ 2];
                const float rot = (nt < 2) ? -part : part;
                outv[nt] = vals[nt] * cs + rot * sn;
            }
        } else {
#pragma unroll
            for (int nt = 0; nt < 4; ++nt) outv[nt] = vals[nt];
        }
        const size_t crow = (size_t)m * N + n0;
        if (of32) {
            float* cp = (float*)Cp + crow;
#pragma unroll
            for (int nt = 0; nt < 4; ++nt) cp[nt * 16 + l16] = outv[nt];
        } else {
            unsigned short* cp = (unsigned short*)Cp + crow;
#pragma unroll
            for (int nt = 0; nt < 4; ++nt) cp[nt * 16 + l16] = f2bf(outv[nt]);
        }
    }
}

__global__ __launch_bounds__(256) void attn_kernel(const unsigned short* __restrict__ Q,
                                                   const unsigned short* __restrict__ Kb,
                                                   const unsigned short* __restrict__ Vb,
                                                   unsigned short* __restrict__ O, int kvs) {
    __shared__ unsigned short lp[4][16][32];

    const int wave = threadIdx.x >> 6;
    const int lane = threadIdx.x & 63;
    const int l16  = lane & 15;
    const int quad = lane >> 4;

    const int bid = blockIdx.x;
    const int qb  = bid & 31;
    const int h   = (bid >> 5) & 31;
    const int b   = bid >> 10;
    const int kvh = h >> 2;
    const int q0  = qb * 64 + wave * 16;

    const unsigned short* qbase = Q + (size_t)b * S_LEN * D_MODEL + h * HEAD_DIM;
    const unsigned short* kbase = Kb + (size_t)b * S_LEN * kvs + kvh * HEAD_DIM;
    const unsigned short* vbase = Vb + (size_t)b * S_LEN * kvs + kvh * HEAD_DIM;

    bf16x8 aq0 = *reinterpret_cast<const bf16x8*>(qbase + (size_t)(q0 + l16) * D_MODEL + quad * 8);
    bf16x8 aq1 = *reinterpret_cast<const bf16x8*>(qbase + (size_t)(q0 + l16) * D_MODEL + 32 + quad * 8);

    f32x4 o[4];
#pragma unroll
    for (int i = 0; i < 4; ++i) o[i] = (f32x4){0.f, 0.f, 0.f, 0.f};
    float mrow[4], lrow[4];
#pragma unroll
    for (int r = 0; r < 4; ++r) { mrow[r] = -3.0e38f; lrow[r] = 0.f; }

    const int kv_hi = qb * 64 + 64;
    for (int k0 = 0; k0 < kv_hi; k0 += 32) {
        f32x4 sc[2];
#pragma unroll
        for (int t = 0; t < 2; ++t) {
            const unsigned short* krow = kbase + (size_t)(k0 + t * 16 + l16) * kvs;
            bf16x8 b0 = *reinterpret_cast<const bf16x8*>(krow + quad * 8);
            bf16x8 b1 = *reinterpret_cast<const bf16x8*>(krow + 32 + quad * 8);
            f32x4 c = (f32x4){0.f, 0.f, 0.f, 0.f};
            c = MFMA16(aq0, b0, c);
            c = MFMA16(aq1, b1, c);
            sc[t] = c;
        }

        float alpha[4], p0v[4], p1v[4];
#pragma unroll
        for (int r = 0; r < 4; ++r) {
            const int qi = q0 + quad * 4 + r;
            float s0 = sc[0][r] * 0.125f;
            float s1 = sc[1][r] * 0.125f;
            if (k0 + l16 > qi)       s0 = -1.0e30f;
            if (k0 + 16 + l16 > qi)  s1 = -1.0e30f;
            float mt = fmaxf(s0, s1);
#pragma unroll
            for (int off = 1; off < 16; off <<= 1) mt = fmaxf(mt, __shfl_xor(mt, off, 64));
            const float mn = fmaxf(mrow[r], mt);
            const float al = __expf(mrow[r] - mn);
            const float p0 = __expf(s0 - mn);
            const float p1 = __expf(s1 - mn);
            float rs = p0 + p1;
#pragma unroll
            for (int off = 1; off < 16; off <<= 1) rs += __shfl_xor(rs, off, 64);
            lrow[r] = lrow[r] * al + rs;
            mrow[r] = mn;
            alpha[r] = al;
            p0v[r] = p0; p1v[r] = p1;
        }
#pragma unroll
        for (int nt = 0; nt < 4; ++nt)
#pragma unroll
            for (int r = 0; r < 4; ++r) o[nt][r] *= alpha[r];

        __syncthreads();
#pragma unroll
        for (int r = 0; r < 4; ++r) {
            lp[wave][quad * 4 + r][l16]      = f2bf(p0v[r]);
            lp[wave][quad * 4 + r][16 + l16] = f2bf(p1v[r]);
        }
        __syncthreads();
        bf16x8 ap = *reinterpret_cast<const bf16x8*>(&lp[wave][l16][quad * 8]);

#pragma unroll
        for (int nt = 0; nt < 4; ++nt) {
            const unsigned short* vcol = vbase + nt * 16 + l16 + (size_t)(k0 + quad * 8) * kvs;
            bf16x8 bv;
#pragma unroll
            for (int j = 0; j < 8; ++j) bv[j] = (short)vcol[(size_t)j * kvs];
            o[nt] = MFMA16(ap, bv, o[nt]);
        }
    }

    unsigned short* obase = O + (size_t)b * S_LEN * D_MODEL + h * HEAD_DIM;
#pragma unroll
    for (int r = 0; r < 4; ++r) {
        const float inv_l = 1.0f / lrow[r];
        unsigned short* orow = obase + (size_t)(q0 + quad * 4 + r) * D_MODEL;
#pragma unroll
        for (int nt = 0; nt < 4; ++nt)
            orow[nt * 16 + l16] = f2bf(o[nt][r] * inv_l);
    }
}

extern "C" void kernel_launch(void* const* d_in, const int* in_sizes, int n_in,
                              void* d_out, int out_size, void* d_ws, size_t ws_size,
                              hipStream_t stream) {
    const void* hidden = d_in[0];
    const void* Wq = d_in[1];
    const void* Wk = d_in[2];
    const void* Wv = d_in[3];
    const void* Wo = d_in[4];
    // d_in[5] = attention_mask: pure causal -1e9 -> implemented directly.

    char* ws = (char*)d_ws;
    int* flag = (int*)ws;
    dim3 blk(256);

    detect_dtype<<<1, blk, 0, stream>>>((const unsigned short*)hidden, flag);

    // kv 8MB + abuf 16MB + hbuf 16MB + wq 8MB + wkv 4MB + wo 8MB + vt 4MB
    const size_t NEED = 1024 + ((size_t)64 << 20);
    if (ws_size >= NEED) {
        unsigned short* kvbuf = (unsigned short*)(ws + 1024);      // [4096,1024]: K cols 0-511, V cols 512-1023
        unsigned short* abuf  = kvbuf + (size_t)4096 * 1024;       // [4096,2048]
        unsigned short* hbuf  = abuf + (size_t)4096 * 2048;        // hidden bf16
        unsigned short* wqb   = hbuf + (size_t)4096 * 2048;        // [2048,2048]
        unsigned short* wkvb  = wqb + (size_t)2048 * 2048;         // [1024,2048]: Wk | Wv
        unsigned short* wob   = wkvb + (size_t)1024 * 2048;        // [2048,2048]
        unsigned short* vtbuf = wob + (size_t)2048 * 2048;         // [2,512,2048] V^T
        unsigned short* qbuf  = (unsigned short*)d_out;            // Q bf16 lives in d_out

        cvt_bf16<<<dim3(2048), blk, 0, stream>>>(hidden, hbuf, M_ROWS * D_MODEL / 8, flag);
        cvt_bf16<<<dim3(1024), blk, 0, stream>>>(Wq, wqb, 2048 * 2048 / 8, flag);
        cvt_bf16<<<dim3(256),  blk, 0, stream>>>(Wk, wkvb, 512 * 2048 / 8, flag);
        cvt_bf16<<<dim3(256),  blk, 0, stream>>>(Wv, wkvb + (size_t)512 * 2048, 512 * 2048 / 8, flag);
        cvt_bf16<<<dim3(1024), blk, 0, stream>>>(Wo, wob, 2048 * 2048 / 8, flag);

        gemm_bt_lds<<<dim3(32, 16), blk, 0, stream>>>(hbuf, wqb, qbuf, 2048, flag, 1, 0);
        gemm_bt_lds<<<dim3(32, 8),  blk, 0, stream>>>(hbuf, wkvb, kvbuf, 1024, flag, 2, 0);
        transpose_v<<<dim3(512), blk, 0, stream>>>(kvbuf + 512, vtbuf);
        attn_kernel2<<<dim3(2 * NHEAD * (S_LEN / 128)), blk, 0, stream>>>(qbuf, kvbuf, vtbuf, abuf, 1024);
        gemm_bt_lds<<<dim3(32, 16), blk, 0, stream>>>(abuf, wob, d_out, 2048, flag, 0, 1);
    } else {
        // legacy 24MB path
        unsigned short* kbuf = (unsigned short*)(ws + 1024);
        unsigned short* vbuf = (unsigned short*)(ws + 1024 + (4u << 20));
        unsigned short* abuf = (unsigned short*)(ws + 1024 + (8u << 20));
        unsigned short* qbuf = (unsigned short*)d_out;
        gemm_bt<<<dim3(M_ROWS / 64, D_MODEL / 64), blk, 0, stream>>>(hidden, Wq, qbuf, D_MODEL, flag, 1, 1, 0);
        gemm_bt<<<dim3(M_ROWS / 64, (NKVH * HEAD_DIM) / 64), blk, 0, stream>>>(hidden, Wk, kbuf, NKVH * HEAD_DIM, flag, 1, 1, 0);
        gemm_bt<<<dim3(M_ROWS / 64, (NKVH * HEAD_DIM) / 64), blk, 0, stream>>>(hidden, Wv, vbuf, NKVH * HEAD_DIM, flag, 1, 0, 0);
        attn_kernel<<<dim3(2 * NHEAD * (S_LEN / 64)), blk, 0, stream>>>(qbuf, kbuf, vbuf, abuf, 512);
        gemm_bt<<<dim3(M_ROWS / 64, D_MODEL / 64), blk, 0, stream>>>(abuf, Wo, d_out, D_MODEL, flag, 0, 0, 1);
    }
}

// Round 3
// 550.616 us; speedup vs baseline: 3.4249x; 1.1425x over previous
//
#include <hip/hip_runtime.h>

// FlashAttentionWrapper: B=2, S=2048, D=2048, NH=32, HD=64, NKV=8, NREP=4,
// causal, RoPE theta=1e4. Input dtype (bf16/f32) detected at runtime.
// New-path workspace (64MB+1KB):
//   [flag 4B pad 1KB][kvbuf 4096x1024 8MB][abuf 4096x2048 16MB]
//   [hbuf 16MB][wqb 8MB][wkvb 4MB][wob 8MB][vtbuf 2x512x2048 4MB]
// Q-projection result lives in d_out (dead before O-proj overwrites it).
// Fallback path (ws < 64MB+1KB): original direct-load kernels, 24MB+1KB.

#define S_LEN 2048
#define D_MODEL 2048
#define NHEAD 32
#define HEAD_DIM 64
#define NKVH 8
#define M_ROWS 4096   // B*S
#define KVW (NKVH * HEAD_DIM)   // 512

typedef __attribute__((ext_vector_type(4))) float f32x4;
typedef __attribute__((ext_vector_type(8))) short bf16x8;

#define MFMA16(a, b, c) __builtin_amdgcn_mfma_f32_16x16x32_bf16((a), (b), (c), 0, 0, 0)

// async global->LDS, 16B per lane; LDS dest is wave-uniform base + lane*16
#define GLOAD_LDS16(g, l)                                                     \
    __builtin_amdgcn_global_load_lds(                                         \
        (const __attribute__((address_space(1))) void*)(g),                   \
        (__attribute__((address_space(3))) void*)(l), 16, 0, 0)

static __device__ __forceinline__ unsigned short f2bf(float f) {
    union { float f; unsigned int i; } v; v.f = f;
    unsigned int x = v.i;
    unsigned int r = (x + 0x7fffu + ((x >> 16) & 1u)) >> 16;  // RNE
    return (unsigned short)r;
}

// ---------------------------------------------------------------------------
// Dtype detection: f32 data read as uint16 shows impossible bf16 exponents at
// even indices.
// ---------------------------------------------------------------------------
__global__ __launch_bounds__(256) void detect_dtype(const unsigned short* __restrict__ h,
                                                    int* __restrict__ flag) {
    __shared__ int cnt;
    if (threadIdx.x == 0) cnt = 0;
    __syncthreads();
    const unsigned short v = h[2 * threadIdx.x];
    const int e = (v >> 7) & 0xFF;
    if (e >= 0x8D) atomicAdd(&cnt, 1);
    __syncthreads();
    if (threadIdx.x == 0) *flag = (cnt >= 8) ? 1 : 0;
}

static __device__ __forceinline__ bf16x8 load_frag(bool f32p, const void* p, size_t off) {
    if (f32p) {
        const float* fp = (const float*)p + off;
        f32x4 x = *reinterpret_cast<const f32x4*>(fp);
        f32x4 y = *reinterpret_cast<const f32x4*>(fp + 4);
        bf16x8 r;
        r[0] = (short)f2bf(x[0]); r[1] = (short)f2bf(x[1]);
        r[2] = (short)f2bf(x[2]); r[3] = (short)f2bf(x[3]);
        r[4] = (short)f2bf(y[0]); r[5] = (short)f2bf(y[1]);
        r[6] = (short)f2bf(y[2]); r[7] = (short)f2bf(y[3]);
        return r;
    }
    return *reinterpret_cast<const bf16x8*>((const unsigned short*)p + off);
}

// ---------------------------------------------------------------------------
// One-time f32->bf16 conversion (or bf16 copy). n8 = element count / 8.
// ---------------------------------------------------------------------------
__global__ __launch_bounds__(256) void cvt_bf16(const void* __restrict__ src,
                                                unsigned short* __restrict__ dst,
                                                int n8, const int* __restrict__ flag) {
    const bool f32p = (*flag != 0);
    int i = blockIdx.x * 256 + threadIdx.x;
    const int stride = gridDim.x * 256;
    for (; i < n8; i += stride) {
        bf16x8 v = load_frag(f32p, src, (size_t)i * 8);
        *reinterpret_cast<bf16x8*>(dst + (size_t)i * 8) = v;
    }
}

// ---------------------------------------------------------------------------
// LDS-staged GEMM (m97 structure): C[M,N] = A[M,2048] @ W[N,2048]^T, all bf16.
// 128x128 tile, BK=32, 4 waves 2x2, global_load_lds width=16.
// rope: 0=none, 1=all cols, 2=cols<512 only (fused K|V GEMM).
// ---------------------------------------------------------------------------
__global__ __launch_bounds__(256) void gemm_bt_lds(const unsigned short* __restrict__ A,
                                                   const unsigned short* __restrict__ W,
                                                   void* __restrict__ Cp, int N,
                                                   const int* __restrict__ flag,
                                                   int rope, int finalout) {
    __shared__ unsigned short lds_a[128 * 32];   // 8KB
    __shared__ unsigned short lds_b[128 * 32];   // 8KB

    const int wave = threadIdx.x >> 6;
    const int lane = threadIdx.x & 63;
    const int l16  = lane & 15;
    const int quad = lane >> 4;
    const int wm   = wave >> 1;
    const int wn   = wave & 1;

    const int m0 = blockIdx.x * 128;
    const int n0 = blockIdx.y * 128;

    const int srow = lane >> 2;
    const int scol = (lane & 3) * 8;
    const unsigned short* ag[2];
    const unsigned short* wg[2];
#pragma unroll
    for (int i = 0; i < 2; ++i) {
        const int c = wave * 2 + i;
        ag[i] = A + (size_t)(m0 + c * 16 + srow) * D_MODEL + scol;
        wg[i] = W + (size_t)(n0 + c * 16 + srow) * D_MODEL + scol;
    }

    f32x4 acc[4][4];
#pragma unroll
    for (int i = 0; i < 4; ++i)
#pragma unroll
        for (int j = 0; j < 4; ++j) acc[i][j] = (f32x4){0.f, 0.f, 0.f, 0.f};

    for (int k0 = 0; k0 < D_MODEL; k0 += 32) {
#pragma unroll
        for (int i = 0; i < 2; ++i) {
            const int c = wave * 2 + i;
            GLOAD_LDS16(ag[i] + k0, &lds_a[c * 512]);
            GLOAD_LDS16(wg[i] + k0, &lds_b[c * 512]);
        }
        __syncthreads();

        bf16x8 af[4], bfm[4];
#pragma unroll
        for (int t = 0; t < 4; ++t) {
            af[t]  = *reinterpret_cast<const bf16x8*>(&lds_a[(wm * 64 + t * 16 + l16) * 32 + quad * 8]);
            bfm[t] = *reinterpret_cast<const bf16x8*>(&lds_b[(wn * 64 + t * 16 + l16) * 32 + quad * 8]);
        }
#pragma unroll
        for (int mt = 0; mt < 4; ++mt)
#pragma unroll
            for (int nt = 0; nt < 4; ++nt)
                acc[mt][nt] = MFMA16(af[mt], bfm[nt], acc[mt][nt]);
        __syncthreads();
    }

    const bool isf32 = (*flag != 0);
    const bool of32  = isf32 && (finalout != 0);
    const bool do_rope = (rope == 1) || (rope == 2 && (n0 + wn * 64) < KVW);
    const int ncol0 = n0 + wn * 64;

#pragma unroll
    for (int mt = 0; mt < 4; ++mt) {
#pragma unroll
        for (int r = 0; r < 4; ++r) {
            const int m = m0 + wm * 64 + mt * 16 + quad * 4 + r;
            float vals[4];
#pragma unroll
            for (int nt = 0; nt < 4; ++nt) vals[nt] = acc[mt][nt][r];
            float outv[4];
            if (do_rope) {
                const float sf = (float)(m & (S_LEN - 1));
#pragma unroll
                for (int nt = 0; nt < 4; ++nt) {
                    const int d = nt * 16 + l16;
                    const float inv = exp2f(-(float)(d & 31) * 0.4152410118609203f);
                    const float th = sf * inv;
                    float sn, cs;
                    sincosf(th, &sn, &cs);
                    const float part = vals[nt ^ 2];
                    const float rot = (nt < 2) ? -part : part;
                    outv[nt] = vals[nt] * cs + rot * sn;
                }
            } else {
#pragma unroll
                for (int nt = 0; nt < 4; ++nt) outv[nt] = vals[nt];
            }
            const size_t crow = (size_t)m * N + ncol0;
            if (of32) {
                float* cp = (float*)Cp + crow;
#pragma unroll
                for (int nt = 0; nt < 4; ++nt) cp[nt * 16 + l16] = outv[nt];
            } else {
                unsigned short* cp = (unsigned short*)Cp + crow;
#pragma unroll
                for (int nt = 0; nt < 4; ++nt) cp[nt * 16 + l16] = f2bf(outv[nt]);
            }
        }
    }
}

// ---------------------------------------------------------------------------
// V transpose: Vsrc = kvbuf V-half [B*S rows, stride 1024] cols 0..511
//   -> Vt[b][c][s] ([B][512][S]).  64x64 LDS tiles, fully coalesced.
// ---------------------------------------------------------------------------
__global__ __launch_bounds__(256) void transpose_v(const unsigned short* __restrict__ Vsrc,
                                                   unsigned short* __restrict__ Vt) {
    __shared__ unsigned short t[64][72];
    const int bid = blockIdx.x;
    const int ct = bid & 7;            // 8 col-tiles (512/64)
    const int st = (bid >> 3) & 31;    // 32 s-tiles (2048/64)
    const int b  = bid >> 8;
    const unsigned short* src = Vsrc + ((size_t)b * S_LEN + st * 64) * 1024 + ct * 64;
    unsigned short* dst = Vt + ((size_t)b * KVW + ct * 64) * S_LEN + st * 64;
    const int r0 = threadIdx.x >> 3;
    const int c0 = (threadIdx.x & 7) * 8;
#pragma unroll
    for (int h = 0; h < 2; ++h) {
        bf16x8 v = *reinterpret_cast<const bf16x8*>(src + (size_t)(r0 + h * 32) * 1024 + c0);
        *reinterpret_cast<bf16x8*>(&t[r0 + h * 32][c0]) = v;
    }
    __syncthreads();
#pragma unroll
    for (int h = 0; h < 2; ++h) {
        const int cr = r0 + h * 32;
        bf16x8 v;
#pragma unroll
        for (int j = 0; j < 8; ++j) v[j] = (short)t[c0 + j][cr];
        *reinterpret_cast<bf16x8*>(dst + (size_t)cr * S_LEN + c0) = v;
    }
}

// ---------------------------------------------------------------------------
// Flash attention v3: causal, GQA. 4 independent waves/block, 32 q-rows/wave,
// 64-key tiles. Causal-paired q-tiles (qt and 15-qt) per block -> uniform
// work, grid 512 blocks. Register software-pipeline: double-buffered K
// fragments (2x-unrolled loop, static indices), V fragments issued before
// the softmax VALU phase. No block barriers (P tile is per-wave LDS; DS pipe
// is in-order within a wave).
// ---------------------------------------------------------------------------
struct AttnCtx {
    const unsigned short* qbase;
    const unsigned short* kbase;
    const unsigned short* vtbase;
    unsigned short* obase;
    int kvs;
    int l16, quad;
    unsigned short (*lpw)[72];   // [32][72] per-wave slice
};

static __device__ __forceinline__ void attn_qtile(const AttnCtx& cx, int q0w) {
    const int l16 = cx.l16, quad = cx.quad;
    const int kvs = cx.kvs;

    // Q fragments: rows q0w + m*16 + l16, k = kh*32 + quad*8 + j
    bf16x8 aq[2][2];
#pragma unroll
    for (int m = 0; m < 2; ++m)
#pragma unroll
        for (int kh = 0; kh < 2; ++kh)
            aq[m][kh] = *reinterpret_cast<const bf16x8*>(
                cx.qbase + (size_t)(q0w + m * 16 + l16) * D_MODEL + kh * 32 + quad * 8);

    f32x4 o[2][4];
#pragma unroll
    for (int m = 0; m < 2; ++m)
#pragma unroll
        for (int i = 0; i < 4; ++i) o[m][i] = (f32x4){0.f, 0.f, 0.f, 0.f};
    float mrow[2][4], lrow[2][4];
#pragma unroll
    for (int m = 0; m < 2; ++m)
#pragma unroll
        for (int r = 0; r < 4; ++r) { mrow[m][r] = -3.0e38f; lrow[m][r] = 0.f; }

    const int kv_hi = q0w + 32;   // per-wave causal bound

    bf16x8 kfa[8], kfb[8];        // K frags [t*2+kh], double-buffered

#define LOADK(DST, KK0)                                                       \
    {                                                                         \
        _Pragma("unroll")                                                     \
        for (int t = 0; t < 4; ++t) {                                         \
            const unsigned short* krow =                                      \
                cx.kbase + (size_t)((KK0) + t * 16 + l16) * kvs;              \
            DST[2 * t]     = *reinterpret_cast<const bf16x8*>(krow + quad * 8);       \
            DST[2 * t + 1] = *reinterpret_cast<const bf16x8*>(krow + 32 + quad * 8);  \
        }                                                                     \
    }

    // Body: QK^T from CUR, prefetch NXT (k0+64), issue V loads, softmax, PV.
#define ATTN_BODY(CUR, NXT)                                                   \
    {                                                                         \
        f32x4 sc[2][4];                                                       \
        _Pragma("unroll")                                                     \
        for (int t = 0; t < 4; ++t) {                                         \
            _Pragma("unroll")                                                 \
            for (int m = 0; m < 2; ++m) {                                     \
                f32x4 c = (f32x4){0.f, 0.f, 0.f, 0.f};                        \
                c = MFMA16(aq[m][0], CUR[2 * t], c);                          \
                c = MFMA16(aq[m][1], CUR[2 * t + 1], c);                      \
                sc[m][t] = c;                                                 \
            }                                                                 \
        }                                                                     \
        if (k0 + 64 < kv_hi) LOADK(NXT, k0 + 64);                             \
        bf16x8 vf[8];                                                         \
        _Pragma("unroll")                                                     \
        for (int nt = 0; nt < 4; ++nt) {                                      \
            const unsigned short* vrow =                                      \
                cx.vtbase + (size_t)(nt * 16 + l16) * S_LEN + k0 + quad * 8;  \
            vf[2 * nt]     = *reinterpret_cast<const bf16x8*>(vrow);          \
            vf[2 * nt + 1] = *reinterpret_cast<const bf16x8*>(vrow + 32);     \
        }                                                                     \
        const bool full = (k0 + 63 <= q0w);                                   \
        float alpha[2][4];                                                    \
        _Pragma("unroll")                                                     \
        for (int m = 0; m < 2; ++m) {                                         \
            _Pragma("unroll")                                                 \
            for (int r = 0; r < 4; ++r) {                                     \
                const int qi = q0w + m * 16 + quad * 4 + r;                   \
                float s[4];                                                   \
                _Pragma("unroll")                                             \
                for (int t = 0; t < 4; ++t) s[t] = sc[m][t][r] * 0.125f;      \
                if (!full) {                                                  \
                    _Pragma("unroll")                                         \
                    for (int t = 0; t < 4; ++t)                               \
                        if (k0 + t * 16 + l16 > qi) s[t] = -1.0e30f;          \
                }                                                             \
                float mt = fmaxf(fmaxf(s[0], s[1]), fmaxf(s[2], s[3]));       \
                _Pragma("unroll")                                             \
                for (int off = 1; off < 16; off <<= 1)                        \
                    mt = fmaxf(mt, __shfl_xor(mt, off, 64));                  \
                const float mn = fmaxf(mrow[m][r], mt);                       \
                const float al = __expf(mrow[m][r] - mn);                     \
                float p[4], rs = 0.f;                                         \
                _Pragma("unroll")                                             \
                for (int t = 0; t < 4; ++t) { p[t] = __expf(s[t] - mn); rs += p[t]; } \
                _Pragma("unroll")                                             \
                for (int off = 1; off < 16; off <<= 1) rs += __shfl_xor(rs, off, 64); \
                lrow[m][r] = lrow[m][r] * al + rs;                            \
                mrow[m][r] = mn;                                              \
                alpha[m][r] = al;                                             \
                _Pragma("unroll")                                             \
                for (int t = 0; t < 4; ++t)                                   \
                    cx.lpw[m * 16 + quad * 4 + r][t * 16 + l16] = f2bf(p[t]); \
            }                                                                 \
        }                                                                     \
        _Pragma("unroll")                                                     \
        for (int m = 0; m < 2; ++m)                                           \
            _Pragma("unroll")                                                 \
            for (int nt = 0; nt < 4; ++nt)                                    \
                _Pragma("unroll")                                             \
                for (int r = 0; r < 4; ++r) o[m][nt][r] *= alpha[m][r];       \
        asm volatile("" ::: "memory");                                        \
        bf16x8 ap[2][2];                                                      \
        _Pragma("unroll")                                                     \
        for (int m = 0; m < 2; ++m)                                           \
            _Pragma("unroll")                                                 \
            for (int kh = 0; kh < 2; ++kh)                                    \
                ap[m][kh] = *reinterpret_cast<const bf16x8*>(                 \
                    &cx.lpw[m * 16 + l16][kh * 32 + quad * 8]);               \
        _Pragma("unroll")                                                     \
        for (int nt = 0; nt < 4; ++nt)                                        \
            _Pragma("unroll")                                                 \
            for (int m = 0; m < 2; ++m) {                                     \
                o[m][nt] = MFMA16(ap[m][0], vf[2 * nt], o[m][nt]);            \
                o[m][nt] = MFMA16(ap[m][1], vf[2 * nt + 1], o[m][nt]);        \
            }                                                                 \
    }

    LOADK(kfa, 0);
    int k0 = 0;
    for (;;) {
        ATTN_BODY(kfa, kfb);
        k0 += 64;
        if (k0 >= kv_hi) break;
        ATTN_BODY(kfb, kfa);
        k0 += 64;
        if (k0 >= kv_hi) break;
    }
#undef ATTN_BODY
#undef LOADK

    // ---- normalize + store (bf16) ----
#pragma unroll
    for (int m = 0; m < 2; ++m)
#pragma unroll
        for (int r = 0; r < 4; ++r) {
            const float inv_l = 1.0f / lrow[m][r];
            unsigned short* orow = cx.obase + (size_t)(q0w + m * 16 + quad * 4 + r) * D_MODEL;
#pragma unroll
            for (int nt = 0; nt < 4; ++nt)
                orow[nt * 16 + l16] = f2bf(o[m][nt][r] * inv_l);
        }
}

__global__ __launch_bounds__(256) void attn_kernel3(const unsigned short* __restrict__ Q,
                                                    const unsigned short* __restrict__ Kb,
                                                    const unsigned short* __restrict__ Vt,
                                                    unsigned short* __restrict__ O, int kvs) {
    __shared__ unsigned short lp[4][32][72];   // per-wave P (32 q x 64 k), padded

    const int wave = threadIdx.x >> 6;
    const int lane = threadIdx.x & 63;

    const int bid = blockIdx.x;
    const int p   = bid & 7;                    // pair index: q-tiles p and 15-p
    const int h   = (bid >> 3) & (NHEAD - 1);
    const int b   = bid >> 8;
    const int kvh = h >> 2;

    AttnCtx cx;
    cx.qbase  = Q + (size_t)b * S_LEN * D_MODEL + h * HEAD_DIM;
    cx.kbase  = Kb + (size_t)b * S_LEN * kvs + kvh * HEAD_DIM;
    cx.vtbase = Vt + ((size_t)b * KVW + kvh * HEAD_DIM) * S_LEN;
    cx.obase  = O + (size_t)b * S_LEN * D_MODEL + h * HEAD_DIM;
    cx.kvs    = kvs;
    cx.l16    = lane & 15;
    cx.quad   = lane >> 4;
    cx.lpw    = lp[wave];

    attn_qtile(cx, p * 128 + wave * 32);                 // light tile
    attn_qtile(cx, (15 - p) * 128 + wave * 32);          // heavy tile
}

// ---------------------------------------------------------------------------
// Legacy direct-load GEMM + attention (fallback path only).
// ---------------------------------------------------------------------------
__global__ __launch_bounds__(256) void gemm_bt(const void* __restrict__ Ap,
                                               const void* __restrict__ Wp,
                                               void* __restrict__ Cp, int N,
                                               const int* __restrict__ flag,
                                               int a_input, int rope, int finalout) {
    const bool isf32 = (*flag != 0);
    const bool af32 = isf32 && (a_input != 0);
    const bool wf32 = isf32;
    const bool of32 = isf32 && (finalout != 0);

    const int wave = threadIdx.x >> 6;
    const int lane = threadIdx.x & 63;
    const int l16  = lane & 15;
    const int quad = lane >> 4;
    const int m0 = blockIdx.x * 64 + wave * 16;
    const int n0 = blockIdx.y * 64;

    f32x4 acc[4];
#pragma unroll
    for (int i = 0; i < 4; ++i) acc[i] = (f32x4){0.f, 0.f, 0.f, 0.f};

    const size_t aoff = (size_t)(m0 + l16) * D_MODEL + quad * 8;
    size_t woff[4];
#pragma unroll
    for (int nt = 0; nt < 4; ++nt)
        woff[nt] = (size_t)(n0 + nt * 16 + l16) * D_MODEL + quad * 8;

    for (int k0 = 0; k0 < D_MODEL; k0 += 32) {
        bf16x8 a = load_frag(af32, Ap, aoff + k0);
#pragma unroll
        for (int nt = 0; nt < 4; ++nt) {
            bf16x8 b = load_frag(wf32, Wp, woff[nt] + k0);
            acc[nt] = MFMA16(a, b, acc[nt]);
        }
    }

#pragma unroll
    for (int r = 0; r < 4; ++r) {
        const int m = m0 + quad * 4 + r;
        float vals[4];
#pragma unroll
        for (int nt = 0; nt < 4; ++nt) vals[nt] = acc[nt][r];
        float outv[4];
        if (rope) {
            const float sf = (float)(m & (S_LEN - 1));
#pragma unroll
            for (int nt = 0; nt < 4; ++nt) {
                const int d = nt * 16 + l16;
                const float inv = exp2f(-(float)(d & 31) * 0.4152410118609203f);
                const float th = sf * inv;
                float sn, cs;
                sincosf(th, &sn, &cs);
                const float part = vals[nt ^ 2];
                const float rot = (nt < 2) ? -part : part;
                outv[nt] = vals[nt] * cs + rot * sn;
            }
        } else {
#pragma unroll
            for (int nt = 0; nt < 4; ++nt) outv[nt] = vals[nt];
        }
        const size_t crow = (size_t)m * N + n0;
        if (of32) {
            float* cp = (float*)Cp + crow;
#pragma unroll
            for (int nt = 0; nt < 4; ++nt) cp[nt * 16 + l16] = outv[nt];
        } else {
            unsigned short* cp = (unsigned short*)Cp + crow;
#pragma unroll
            for (int nt = 0; nt < 4; ++nt) cp[nt * 16 + l16] = f2bf(outv[nt]);
        }
    }
}

__global__ __launch_bounds__(256) void attn_kernel(const unsigned short* __restrict__ Q,
                                                   const unsigned short* __restrict__ Kb,
                                                   const unsigned short* __restrict__ Vb,
                                                   unsigned short* __restrict__ O, int kvs) {
    __shared__ unsigned short lp[4][16][32];

    const int wave = threadIdx.x >> 6;
    const int lane = threadIdx.x & 63;
    const int l16  = lane & 15;
    const int quad = lane >> 4;

    const int bid = blockIdx.x;
    const int qb  = bid & 31;
    const int h   = (bid >> 5) & 31;
    const int b   = bid >> 10;
    const int kvh = h >> 2;
    const int q0  = qb * 64 + wave * 16;

    const unsigned short* qbase = Q + (size_t)b * S_LEN * D_MODEL + h * HEAD_DIM;
    const unsigned short* kbase = Kb + (size_t)b * S_LEN * kvs + kvh * HEAD_DIM;
    const unsigned short* vbase = Vb + (size_t)b * S_LEN * kvs + kvh * HEAD_DIM;

    bf16x8 aq0 = *reinterpret_cast<const bf16x8*>(qbase + (size_t)(q0 + l16) * D_MODEL + quad * 8);
    bf16x8 aq1 = *reinterpret_cast<const bf16x8*>(qbase + (size_t)(q0 + l16) * D_MODEL + 32 + quad * 8);

    f32x4 o[4];
#pragma unroll
    for (int i = 0; i < 4; ++i) o[i] = (f32x4){0.f, 0.f, 0.f, 0.f};
    float mrow[4], lrow[4];
#pragma unroll
    for (int r = 0; r < 4; ++r) { mrow[r] = -3.0e38f; lrow[r] = 0.f; }

    const int kv_hi = qb * 64 + 64;
    for (int k0 = 0; k0 < kv_hi; k0 += 32) {
        f32x4 sc[2];
#pragma unroll
        for (int t = 0; t < 2; ++t) {
            const unsigned short* krow = kbase + (size_t)(k0 + t * 16 + l16) * kvs;
            bf16x8 b0 = *reinterpret_cast<const bf16x8*>(krow + quad * 8);
            bf16x8 b1 = *reinterpret_cast<const bf16x8*>(krow + 32 + quad * 8);
            f32x4 c = (f32x4){0.f, 0.f, 0.f, 0.f};
            c = MFMA16(aq0, b0, c);
            c = MFMA16(aq1, b1, c);
            sc[t] = c;
        }

        float alpha[4], p0v[4], p1v[4];
#pragma unroll
        for (int r = 0; r < 4; ++r) {
            const int qi = q0 + quad * 4 + r;
            float s0 = sc[0][r] * 0.125f;
            float s1 = sc[1][r] * 0.125f;
            if (k0 + l16 > qi)       s0 = -1.0e30f;
            if (k0 + 16 + l16 > qi)  s1 = -1.0e30f;
            float mt = fmaxf(s0, s1);
#pragma unroll
            for (int off = 1; off < 16; off <<= 1) mt = fmaxf(mt, __shfl_xor(mt, off, 64));
            const float mn = fmaxf(mrow[r], mt);
            const float al = __expf(mrow[r] - mn);
            const float p0 = __expf(s0 - mn);
            const float p1 = __expf(s1 - mn);
            float rs = p0 + p1;
#pragma unroll
            for (int off = 1; off < 16; off <<= 1) rs += __shfl_xor(rs, off, 64);
            lrow[r] = lrow[r] * al + rs;
            mrow[r] = mn;
            alpha[r] = al;
            p0v[r] = p0; p1v[r] = p1;
        }
#pragma unroll
        for (int nt = 0; nt < 4; ++nt)
#pragma unroll
            for (int r = 0; r < 4; ++r) o[nt][r] *= alpha[r];

        __syncthreads();
#pragma unroll
        for (int r = 0; r < 4; ++r) {
            lp[wave][quad * 4 + r][l16]      = f2bf(p0v[r]);
            lp[wave][quad * 4 + r][16 + l16] = f2bf(p1v[r]);
        }
        __syncthreads();
        bf16x8 ap = *reinterpret_cast<const bf16x8*>(&lp[wave][l16][quad * 8]);

#pragma unroll
        for (int nt = 0; nt < 4; ++nt) {
            const unsigned short* vcol = vbase + nt * 16 + l16 + (size_t)(k0 + quad * 8) * kvs;
            bf16x8 bv;
#pragma unroll
            for (int j = 0; j < 8; ++j) bv[j] = (short)vcol[(size_t)j * kvs];
            o[nt] = MFMA16(ap, bv, o[nt]);
        }
    }

    unsigned short* obase = O + (size_t)b * S_LEN * D_MODEL + h * HEAD_DIM;
#pragma unroll
    for (int r = 0; r < 4; ++r) {
        const float inv_l = 1.0f / lrow[r];
        unsigned short* orow = obase + (size_t)(q0 + quad * 4 + r) * D_MODEL;
#pragma unroll
        for (int nt = 0; nt < 4; ++nt)
            orow[nt * 16 + l16] = f2bf(o[nt][r] * inv_l);
    }
}

extern "C" void kernel_launch(void* const* d_in, const int* in_sizes, int n_in,
                              void* d_out, int out_size, void* d_ws, size_t ws_size,
                              hipStream_t stream) {
    const void* hidden = d_in[0];
    const void* Wq = d_in[1];
    const void* Wk = d_in[2];
    const void* Wv = d_in[3];
    const void* Wo = d_in[4];
    // d_in[5] = attention_mask: pure causal -1e9 -> implemented directly.

    char* ws = (char*)d_ws;
    int* flag = (int*)ws;
    dim3 blk(256);

    detect_dtype<<<1, blk, 0, stream>>>((const unsigned short*)hidden, flag);

    // kv 8MB + abuf 16MB + hbuf 16MB + wq 8MB + wkv 4MB + wo 8MB + vt 4MB
    const size_t NEED = 1024 + ((size_t)64 << 20);
    if (ws_size >= NEED) {
        unsigned short* kvbuf = (unsigned short*)(ws + 1024);      // [4096,1024]: K cols 0-511, V cols 512-1023
        unsigned short* abuf  = kvbuf + (size_t)4096 * 1024;       // [4096,2048]
        unsigned short* hbuf  = abuf + (size_t)4096 * 2048;        // hidden bf16
        unsigned short* wqb   = hbuf + (size_t)4096 * 2048;        // [2048,2048]
        unsigned short* wkvb  = wqb + (size_t)2048 * 2048;         // [1024,2048]: Wk | Wv
        unsigned short* wob   = wkvb + (size_t)1024 * 2048;        // [2048,2048]
        unsigned short* vtbuf = wob + (size_t)2048 * 2048;         // [2,512,2048] V^T
        unsigned short* qbuf  = (unsigned short*)d_out;            // Q bf16 lives in d_out

        cvt_bf16<<<dim3(2048), blk, 0, stream>>>(hidden, hbuf, M_ROWS * D_MODEL / 8, flag);
        cvt_bf16<<<dim3(1024), blk, 0, stream>>>(Wq, wqb, 2048 * 2048 / 8, flag);
        cvt_bf16<<<dim3(256),  blk, 0, stream>>>(Wk, wkvb, 512 * 2048 / 8, flag);
        cvt_bf16<<<dim3(256),  blk, 0, stream>>>(Wv, wkvb + (size_t)512 * 2048, 512 * 2048 / 8, flag);
        cvt_bf16<<<dim3(1024), blk, 0, stream>>>(Wo, wob, 2048 * 2048 / 8, flag);

        gemm_bt_lds<<<dim3(32, 16), blk, 0, stream>>>(hbuf, wqb, qbuf, 2048, flag, 1, 0);
        gemm_bt_lds<<<dim3(32, 8),  blk, 0, stream>>>(hbuf, wkvb, kvbuf, 1024, flag, 2, 0);
        transpose_v<<<dim3(512), blk, 0, stream>>>(kvbuf + 512, vtbuf);
        attn_kernel3<<<dim3(2 * NHEAD * (S_LEN / 256)), blk, 0, stream>>>(qbuf, kvbuf, vtbuf, abuf, 1024);
        gemm_bt_lds<<<dim3(32, 16), blk, 0, stream>>>(abuf, wob, d_out, 2048, flag, 0, 1);
    } else {
        // legacy 24MB path
        unsigned short* kbuf = (unsigned short*)(ws + 1024);
        unsigned short* vbuf = (unsigned short*)(ws + 1024 + (4u << 20));
        unsigned short* abuf = (unsigned short*)(ws + 1024 + (8u << 20));
        unsigned short* qbuf = (unsigned short*)d_out;
        gemm_bt<<<dim3(M_ROWS / 64, D_MODEL / 64), blk, 0, stream>>>(hidden, Wq, qbuf, D_MODEL, flag, 1, 1, 0);
        gemm_bt<<<dim3(M_ROWS / 64, (NKVH * HEAD_DIM) / 64), blk, 0, stream>>>(hidden, Wk, kbuf, NKVH * HEAD_DIM, flag, 1, 1, 0);
        gemm_bt<<<dim3(M_ROWS / 64, (NKVH * HEAD_DIM) / 64), blk, 0, stream>>>(hidden, Wv, vbuf, NKVH * HEAD_DIM, flag, 1, 0, 0);
        attn_kernel<<<dim3(2 * NHEAD * (S_LEN / 64)), blk, 0, stream>>>(qbuf, kbuf, vbuf, abuf, 512);
        gemm_bt<<<dim3(M_ROWS / 64, D_MODEL / 64), blk, 0, stream>>>(abuf, Wo, d_out, D_MODEL, flag, 0, 0, 1);
    }
}

// Round 4
// 445.208 us; speedup vs baseline: 4.2357x; 1.2368x over previous
//
#include <hip/hip_runtime.h>

// FlashAttentionWrapper: B=2, S=2048, D=2048, NH=32, HD=64, NKV=8, NREP=4,
// causal, RoPE theta=1e4. Input dtype (bf16/f32) detected at runtime.
// New-path workspace (64MB+1KB):
//   [flag 4B pad 1KB][kvbuf 4096x1024 8MB][abuf 4096x2048 16MB]
//   [hbuf 16MB][wqb 8MB][wkvb 4MB][wob 8MB][vtbuf 2x512x2048 4MB]
// Q-projection result lives in d_out (dead before O-proj overwrites it).
// Fallback path (ws < 64MB+1KB): original direct-load kernels, 24MB+1KB.

#define S_LEN 2048
#define D_MODEL 2048
#define NHEAD 32
#define HEAD_DIM 64
#define NKVH 8
#define M_ROWS 4096   // B*S
#define KVW (NKVH * HEAD_DIM)   // 512

typedef __attribute__((ext_vector_type(4))) float f32x4;
typedef __attribute__((ext_vector_type(8))) short bf16x8;

#define MFMA16(a, b, c) __builtin_amdgcn_mfma_f32_16x16x32_bf16((a), (b), (c), 0, 0, 0)

// async global->LDS, 16B per lane; LDS dest is wave-uniform base + lane*16
#define GLOAD_LDS16(g, l)                                                     \
    __builtin_amdgcn_global_load_lds(                                         \
        (const __attribute__((address_space(1))) void*)(g),                   \
        (__attribute__((address_space(3))) void*)(l), 16, 0, 0)

static __device__ __forceinline__ unsigned short f2bf(float f) {
    union { float f; unsigned int i; } v; v.f = f;
    unsigned int x = v.i;
    unsigned int r = (x + 0x7fffu + ((x >> 16) & 1u)) >> 16;  // RNE
    return (unsigned short)r;
}

static __device__ __forceinline__ float fexp2(float x) {
#if __has_builtin(__builtin_amdgcn_exp2f)
    return __builtin_amdgcn_exp2f(x);
#else
    return exp2f(x);
#endif
}

// ---------------------------------------------------------------------------
// Dtype detection: f32 data read as uint16 shows impossible bf16 exponents at
// even indices.
// ---------------------------------------------------------------------------
__global__ __launch_bounds__(256) void detect_dtype(const unsigned short* __restrict__ h,
                                                    int* __restrict__ flag) {
    __shared__ int cnt;
    if (threadIdx.x == 0) cnt = 0;
    __syncthreads();
    const unsigned short v = h[2 * threadIdx.x];
    const int e = (v >> 7) & 0xFF;
    if (e >= 0x8D) atomicAdd(&cnt, 1);
    __syncthreads();
    if (threadIdx.x == 0) *flag = (cnt >= 8) ? 1 : 0;
}

static __device__ __forceinline__ bf16x8 load_frag(bool f32p, const void* p, size_t off) {
    if (f32p) {
        const float* fp = (const float*)p + off;
        f32x4 x = *reinterpret_cast<const f32x4*>(fp);
        f32x4 y = *reinterpret_cast<const f32x4*>(fp + 4);
        bf16x8 r;
        r[0] = (short)f2bf(x[0]); r[1] = (short)f2bf(x[1]);
        r[2] = (short)f2bf(x[2]); r[3] = (short)f2bf(x[3]);
        r[4] = (short)f2bf(y[0]); r[5] = (short)f2bf(y[1]);
        r[6] = (short)f2bf(y[2]); r[7] = (short)f2bf(y[3]);
        return r;
    }
    return *reinterpret_cast<const bf16x8*>((const unsigned short*)p + off);
}

// ---------------------------------------------------------------------------
// Fused one-time f32->bf16 conversion (or bf16 copy) of all 5 operands.
// Units of 8 elements; 5 concatenated segments.
// ---------------------------------------------------------------------------
__global__ __launch_bounds__(256) void cvt_all(const void* __restrict__ h,
                                               const void* __restrict__ wq,
                                               const void* __restrict__ wk,
                                               const void* __restrict__ wv,
                                               const void* __restrict__ wo,
                                               unsigned short* __restrict__ hbuf,
                                               unsigned short* __restrict__ wqb,
                                               unsigned short* __restrict__ wkvb,
                                               unsigned short* __restrict__ wob,
                                               const int* __restrict__ flag) {
    const bool f32p = (*flag != 0);
    // segment boundaries (units of 8 elems)
    const int e0 = 1048576;            // hidden 4096x2048
    const int e1 = e0 + 524288;        // Wq 2048x2048
    const int e2 = e1 + 131072;        // Wk 512x2048
    const int e3 = e2 + 131072;        // Wv 512x2048
    const int e4 = e3 + 524288;        // Wo 2048x2048
    int i = blockIdx.x * 256 + threadIdx.x;
    const int stride = gridDim.x * 256;
    for (; i < e4; i += stride) {
        const void* s;
        unsigned short* d;
        size_t off;
        if (i < e0)      { s = h;  d = hbuf; off = (size_t)i; }
        else if (i < e1) { s = wq; d = wqb;  off = (size_t)(i - e0); }
        else if (i < e2) { s = wk; d = wkvb; off = (size_t)(i - e1); }
        else if (i < e3) { s = wv; d = wkvb + (size_t)512 * 2048; off = (size_t)(i - e2); }
        else             { s = wo; d = wob;  off = (size_t)(i - e3); }
        bf16x8 v = load_frag(f32p, s, off * 8);
        *reinterpret_cast<bf16x8*>(d + off * 8) = v;
    }
}

// ---------------------------------------------------------------------------
// LDS-staged GEMM (m97 structure): C[M,N] = A[M,2048] @ W[N,2048]^T, all bf16.
// 128x128 tile, BK=32, 4 waves 2x2, global_load_lds width=16.
// rope: 0=none, 1=all cols, 2=cols<512 only (fused K|V GEMM).
// ---------------------------------------------------------------------------
__global__ __launch_bounds__(256) void gemm_bt_lds(const unsigned short* __restrict__ A,
                                                   const unsigned short* __restrict__ W,
                                                   void* __restrict__ Cp, int N,
                                                   const int* __restrict__ flag,
                                                   int rope, int finalout) {
    __shared__ unsigned short lds_a[128 * 32];   // 8KB
    __shared__ unsigned short lds_b[128 * 32];   // 8KB

    const int wave = threadIdx.x >> 6;
    const int lane = threadIdx.x & 63;
    const int l16  = lane & 15;
    const int quad = lane >> 4;
    const int wm   = wave >> 1;
    const int wn   = wave & 1;

    const int m0 = blockIdx.x * 128;
    const int n0 = blockIdx.y * 128;

    const int srow = lane >> 2;
    const int scol = (lane & 3) * 8;
    const unsigned short* ag[2];
    const unsigned short* wg[2];
#pragma unroll
    for (int i = 0; i < 2; ++i) {
        const int c = wave * 2 + i;
        ag[i] = A + (size_t)(m0 + c * 16 + srow) * D_MODEL + scol;
        wg[i] = W + (size_t)(n0 + c * 16 + srow) * D_MODEL + scol;
    }

    f32x4 acc[4][4];
#pragma unroll
    for (int i = 0; i < 4; ++i)
#pragma unroll
        for (int j = 0; j < 4; ++j) acc[i][j] = (f32x4){0.f, 0.f, 0.f, 0.f};

    for (int k0 = 0; k0 < D_MODEL; k0 += 32) {
#pragma unroll
        for (int i = 0; i < 2; ++i) {
            const int c = wave * 2 + i;
            GLOAD_LDS16(ag[i] + k0, &lds_a[c * 512]);
            GLOAD_LDS16(wg[i] + k0, &lds_b[c * 512]);
        }
        __syncthreads();

        bf16x8 af[4], bfm[4];
#pragma unroll
        for (int t = 0; t < 4; ++t) {
            af[t]  = *reinterpret_cast<const bf16x8*>(&lds_a[(wm * 64 + t * 16 + l16) * 32 + quad * 8]);
            bfm[t] = *reinterpret_cast<const bf16x8*>(&lds_b[(wn * 64 + t * 16 + l16) * 32 + quad * 8]);
        }
#pragma unroll
        for (int mt = 0; mt < 4; ++mt)
#pragma unroll
            for (int nt = 0; nt < 4; ++nt)
                acc[mt][nt] = MFMA16(af[mt], bfm[nt], acc[mt][nt]);
        __syncthreads();
    }

    const bool isf32 = (*flag != 0);
    const bool of32  = isf32 && (finalout != 0);
    const bool do_rope = (rope == 1) || (rope == 2 && (n0 + wn * 64) < KVW);
    const int ncol0 = n0 + wn * 64;

#pragma unroll
    for (int mt = 0; mt < 4; ++mt) {
#pragma unroll
        for (int r = 0; r < 4; ++r) {
            const int m = m0 + wm * 64 + mt * 16 + quad * 4 + r;
            float vals[4];
#pragma unroll
            for (int nt = 0; nt < 4; ++nt) vals[nt] = acc[mt][nt][r];
            float outv[4];
            if (do_rope) {
                const float sf = (float)(m & (S_LEN - 1));
#pragma unroll
                for (int nt = 0; nt < 4; ++nt) {
                    const int d = nt * 16 + l16;
                    const float inv = exp2f(-(float)(d & 31) * 0.4152410118609203f);
                    const float th = sf * inv;
                    float sn, cs;
                    sincosf(th, &sn, &cs);
                    const float part = vals[nt ^ 2];
                    const float rot = (nt < 2) ? -part : part;
                    outv[nt] = vals[nt] * cs + rot * sn;
                }
            } else {
#pragma unroll
                for (int nt = 0; nt < 4; ++nt) outv[nt] = vals[nt];
            }
            const size_t crow = (size_t)m * N + ncol0;
            if (of32) {
                float* cp = (float*)Cp + crow;
#pragma unroll
                for (int nt = 0; nt < 4; ++nt) cp[nt * 16 + l16] = outv[nt];
            } else {
                unsigned short* cp = (unsigned short*)Cp + crow;
#pragma unroll
                for (int nt = 0; nt < 4; ++nt) cp[nt * 16 + l16] = f2bf(outv[nt]);
            }
        }
    }
}

// ---------------------------------------------------------------------------
// V transpose: Vsrc = kvbuf V-half [B*S rows, stride 1024] cols 0..511
//   -> Vt[b][c][s] ([B][512][S]).  64x64 LDS tiles, fully coalesced.
// ---------------------------------------------------------------------------
__global__ __launch_bounds__(256) void transpose_v(const unsigned short* __restrict__ Vsrc,
                                                   unsigned short* __restrict__ Vt) {
    __shared__ unsigned short t[64][72];
    const int bid = blockIdx.x;
    const int ct = bid & 7;            // 8 col-tiles (512/64)
    const int st = (bid >> 3) & 31;    // 32 s-tiles (2048/64)
    const int b  = bid >> 8;
    const unsigned short* src = Vsrc + ((size_t)b * S_LEN + st * 64) * 1024 + ct * 64;
    unsigned short* dst = Vt + ((size_t)b * KVW + ct * 64) * S_LEN + st * 64;
    const int r0 = threadIdx.x >> 3;
    const int c0 = (threadIdx.x & 7) * 8;
#pragma unroll
    for (int h = 0; h < 2; ++h) {
        bf16x8 v = *reinterpret_cast<const bf16x8*>(src + (size_t)(r0 + h * 32) * 1024 + c0);
        *reinterpret_cast<bf16x8*>(&t[r0 + h * 32][c0]) = v;
    }
    __syncthreads();
#pragma unroll
    for (int h = 0; h < 2; ++h) {
        const int cr = r0 + h * 32;
        bf16x8 v;
#pragma unroll
        for (int j = 0; j < 8; ++j) v[j] = (short)t[c0 + j][cr];
        *reinterpret_cast<bf16x8*>(dst + (size_t)cr * S_LEN + c0) = v;
    }
}

// ---------------------------------------------------------------------------
// Flash attention v4: causal, GQA. 4 independent waves/block, 32 q-rows/wave,
// 64-key tiles, causal-paired q-tiles (qt, 15-qt) per block. Softmax in
// log2-domain with DEFERRED max (THR=8: rescale only when the tile max grows
// past m+8; wave-uniform __any branch) and row-sum computed BY MFMA
// (l = P @ ones, same ap fragments as PV). Common path has zero cross-lane
// shuffles. K frags double-buffered; V frags issued before the softmax phase.
// ---------------------------------------------------------------------------
struct AttnCtx {
    const unsigned short* qbase;
    const unsigned short* kbase;
    const unsigned short* vtbase;
    unsigned short* obase;
    int kvs;
    int l16, quad;
    unsigned short (*lpw)[72];   // [32][72] per-wave slice
};

#define SM_C 0.18033688011112042f   // 0.125 * log2(e)
#define SM_THR 8.0f

static __device__ __forceinline__ void attn_qtile(const AttnCtx& cx, int q0w) {
    const int l16 = cx.l16, quad = cx.quad;
    const int kvs = cx.kvs;

    bf16x8 ones;
#pragma unroll
    for (int j = 0; j < 8; ++j) ones[j] = (short)0x3F80;   // bf16 1.0

    // Q fragments: rows q0w + m*16 + l16, k = kh*32 + quad*8 + j
    bf16x8 aq[2][2];
#pragma unroll
    for (int m = 0; m < 2; ++m)
#pragma unroll
        for (int kh = 0; kh < 2; ++kh)
            aq[m][kh] = *reinterpret_cast<const bf16x8*>(
                cx.qbase + (size_t)(q0w + m * 16 + l16) * D_MODEL + kh * 32 + quad * 8);

    f32x4 o[2][4];
    f32x4 c_l[2];     // row-sum accumulator (l = P @ ones)
#pragma unroll
    for (int m = 0; m < 2; ++m) {
#pragma unroll
        for (int i = 0; i < 4; ++i) o[m][i] = (f32x4){0.f, 0.f, 0.f, 0.f};
        c_l[m] = (f32x4){0.f, 0.f, 0.f, 0.f};
    }
    float m2[2][4];   // running max, log2 domain
#pragma unroll
    for (int m = 0; m < 2; ++m)
#pragma unroll
        for (int r = 0; r < 4; ++r) m2[m][r] = 0.f;

    const int kv_hi = q0w + 32;   // per-wave causal bound

    bf16x8 kfa[8], kfb[8];        // K frags [t*2+kh], double-buffered

#define LOADK(DST, KK0)                                                       \
    {                                                                         \
        _Pragma("unroll")                                                     \
        for (int t = 0; t < 4; ++t) {                                         \
            const unsigned short* krow =                                      \
                cx.kbase + (size_t)((KK0) + t * 16 + l16) * kvs;              \
            DST[2 * t]     = *reinterpret_cast<const bf16x8*>(krow + quad * 8);       \
            DST[2 * t + 1] = *reinterpret_cast<const bf16x8*>(krow + 32 + quad * 8);  \
        }                                                                     \
    }

#define ATTN_BODY(CUR, NXT)                                                   \
    {                                                                         \
        f32x4 sc[2][4];                                                       \
        __builtin_amdgcn_s_setprio(1);                                        \
        _Pragma("unroll")                                                     \
        for (int t = 0; t < 4; ++t) {                                         \
            _Pragma("unroll")                                                 \
            for (int m = 0; m < 2; ++m) {                                     \
                f32x4 c = (f32x4){0.f, 0.f, 0.f, 0.f};                        \
                c = MFMA16(aq[m][0], CUR[2 * t], c);                          \
                c = MFMA16(aq[m][1], CUR[2 * t + 1], c);                      \
                sc[m][t] = c;                                                 \
            }                                                                 \
        }                                                                     \
        __builtin_amdgcn_s_setprio(0);                                        \
        if (k0 + 64 < kv_hi) LOADK(NXT, k0 + 64);                             \
        bf16x8 vf[8];                                                         \
        _Pragma("unroll")                                                     \
        for (int nt = 0; nt < 4; ++nt) {                                      \
            const unsigned short* vrow =                                      \
                cx.vtbase + (size_t)(nt * 16 + l16) * S_LEN + k0 + quad * 8;  \
            vf[2 * nt]     = *reinterpret_cast<const bf16x8*>(vrow);          \
            vf[2 * nt + 1] = *reinterpret_cast<const bf16x8*>(vrow + 32);     \
        }                                                                     \
        const bool full = (k0 + 63 <= q0w);                                   \
        /* pass 1: scale to log2 domain, mask, per-lane tile max */           \
        float pm[2][4];                                                       \
        float dif = -3.0e38f;                                                 \
        _Pragma("unroll")                                                     \
        for (int m = 0; m < 2; ++m) {                                         \
            _Pragma("unroll")                                                 \
            for (int r = 0; r < 4; ++r) {                                     \
                const int qi = q0w + m * 16 + quad * 4 + r;                   \
                float s[4];                                                   \
                _Pragma("unroll")                                             \
                for (int t = 0; t < 4; ++t) {                                 \
                    s[t] = sc[m][t][r] * SM_C;                                \
                    if (!full && (k0 + t * 16 + l16 > qi)) s[t] = -1.0e30f;   \
                    sc[m][t][r] = s[t];                                       \
                }                                                             \
                const float p = fmaxf(fmaxf(s[0], s[1]), fmaxf(s[2], s[3])); \
                pm[m][r] = p;                                                 \
                dif = fmaxf(dif, p - m2[m][r]);                               \
            }                                                                 \
        }                                                                     \
        /* rare, wave-uniform rescale */                                      \
        if (__any(dif > SM_THR)) {                                            \
            _Pragma("unroll")                                                 \
            for (int m = 0; m < 2; ++m) {                                     \
                _Pragma("unroll")                                             \
                for (int r = 0; r < 4; ++r) {                                 \
                    float mt = pm[m][r];                                      \
                    _Pragma("unroll")                                         \
                    for (int off = 1; off < 16; off <<= 1)                    \
                        mt = fmaxf(mt, __shfl_xor(mt, off, 64));              \
                    const float mn = fmaxf(m2[m][r], mt);                     \
                    const float al = fexp2(m2[m][r] - mn);                    \
                    m2[m][r] = mn;                                            \
                    _Pragma("unroll")                                         \
                    for (int nt = 0; nt < 4; ++nt) o[m][nt][r] *= al;         \
                    c_l[m][r] *= al;                                          \
                }                                                             \
            }                                                                 \
        }                                                                     \
        /* pass 2: p = 2^(s - m2), write P tile */                            \
        _Pragma("unroll")                                                     \
        for (int m = 0; m < 2; ++m) {                                         \
            _Pragma("unroll")                                                 \
            for (int r = 0; r < 4; ++r) {                                     \
                _Pragma("unroll")                                             \
                for (int t = 0; t < 4; ++t) {                                 \
                    const float pv = fexp2(sc[m][t][r] - m2[m][r]);           \
                    cx.lpw[m * 16 + quad * 4 + r][t * 16 + l16] = f2bf(pv);   \
                }                                                             \
            }                                                                 \
        }                                                                     \
        asm volatile("" ::: "memory");                                        \
        bf16x8 ap[2][2];                                                      \
        _Pragma("unroll")                                                     \
        for (int m = 0; m < 2; ++m)                                           \
            _Pragma("unroll")                                                 \
            for (int kh = 0; kh < 2; ++kh)                                    \
                ap[m][kh] = *reinterpret_cast<const bf16x8*>(                 \
                    &cx.lpw[m * 16 + l16][kh * 32 + quad * 8]);               \
        __builtin_amdgcn_s_setprio(1);                                        \
        _Pragma("unroll")                                                     \
        for (int nt = 0; nt < 4; ++nt)                                        \
            _Pragma("unroll")                                                 \
            for (int m = 0; m < 2; ++m) {                                     \
                o[m][nt] = MFMA16(ap[m][0], vf[2 * nt], o[m][nt]);            \
                o[m][nt] = MFMA16(ap[m][1], vf[2 * nt + 1], o[m][nt]);        \
            }                                                                 \
        _Pragma("unroll")                                                     \
        for (int m = 0; m < 2; ++m) {                                         \
            c_l[m] = MFMA16(ap[m][0], ones, c_l[m]);                          \
            c_l[m] = MFMA16(ap[m][1], ones, c_l[m]);                          \
        }                                                                     \
        __builtin_amdgcn_s_setprio(0);                                        \
    }

    LOADK(kfa, 0);
    int k0 = 0;
    for (;;) {
        ATTN_BODY(kfa, kfb);
        k0 += 64;
        if (k0 >= kv_hi) break;
        ATTN_BODY(kfb, kfa);
        k0 += 64;
        if (k0 >= kv_hi) break;
    }
#undef ATTN_BODY
#undef LOADK

    // ---- normalize + store (bf16) ----
#pragma unroll
    for (int m = 0; m < 2; ++m)
#pragma unroll
        for (int r = 0; r < 4; ++r) {
            const float inv_l = 1.0f / c_l[m][r];
            unsigned short* orow = cx.obase + (size_t)(q0w + m * 16 + quad * 4 + r) * D_MODEL;
#pragma unroll
            for (int nt = 0; nt < 4; ++nt)
                orow[nt * 16 + l16] = f2bf(o[m][nt][r] * inv_l);
        }
}

__global__ __launch_bounds__(256) void attn_kernel4(const unsigned short* __restrict__ Q,
                                                    const unsigned short* __restrict__ Kb,
                                                    const unsigned short* __restrict__ Vt,
                                                    unsigned short* __restrict__ O, int kvs) {
    __shared__ unsigned short lp[4][32][72];   // per-wave P (32 q x 64 k), padded

    const int wave = threadIdx.x >> 6;
    const int lane = threadIdx.x & 63;

    const int bid = blockIdx.x;
    const int p   = bid & 7;                    // pair index: q-tiles p and 15-p
    const int h   = (bid >> 3) & (NHEAD - 1);
    const int b   = bid >> 8;
    const int kvh = h >> 2;

    AttnCtx cx;
    cx.qbase  = Q + (size_t)b * S_LEN * D_MODEL + h * HEAD_DIM;
    cx.kbase  = Kb + (size_t)b * S_LEN * kvs + kvh * HEAD_DIM;
    cx.vtbase = Vt + ((size_t)b * KVW + kvh * HEAD_DIM) * S_LEN;
    cx.obase  = O + (size_t)b * S_LEN * D_MODEL + h * HEAD_DIM;
    cx.kvs    = kvs;
    cx.l16    = lane & 15;
    cx.quad   = lane >> 4;
    cx.lpw    = lp[wave];

    attn_qtile(cx, p * 128 + wave * 32);                 // light tile
    attn_qtile(cx, (15 - p) * 128 + wave * 32);          // heavy tile
}

// ---------------------------------------------------------------------------
// Legacy direct-load GEMM + attention (fallback path only).
// ---------------------------------------------------------------------------
__global__ __launch_bounds__(256) void gemm_bt(const void* __restrict__ Ap,
                                               const void* __restrict__ Wp,
                                               void* __restrict__ Cp, int N,
                                               const int* __restrict__ flag,
                                               int a_input, int rope, int finalout) {
    const bool isf32 = (*flag != 0);
    const bool af32 = isf32 && (a_input != 0);
    const bool wf32 = isf32;
    const bool of32 = isf32 && (finalout != 0);

    const int wave = threadIdx.x >> 6;
    const int lane = threadIdx.x & 63;
    const int l16  = lane & 15;
    const int quad = lane >> 4;
    const int m0 = blockIdx.x * 64 + wave * 16;
    const int n0 = blockIdx.y * 64;

    f32x4 acc[4];
#pragma unroll
    for (int i = 0; i < 4; ++i) acc[i] = (f32x4){0.f, 0.f, 0.f, 0.f};

    const size_t aoff = (size_t)(m0 + l16) * D_MODEL + quad * 8;
    size_t woff[4];
#pragma unroll
    for (int nt = 0; nt < 4; ++nt)
        woff[nt] = (size_t)(n0 + nt * 16 + l16) * D_MODEL + quad * 8;

    for (int k0 = 0; k0 < D_MODEL; k0 += 32) {
        bf16x8 a = load_frag(af32, Ap, aoff + k0);
#pragma unroll
        for (int nt = 0; nt < 4; ++nt) {
            bf16x8 b = load_frag(wf32, Wp, woff[nt] + k0);
            acc[nt] = MFMA16(a, b, acc[nt]);
        }
    }

#pragma unroll
    for (int r = 0; r < 4; ++r) {
        const int m = m0 + quad * 4 + r;
        float vals[4];
#pragma unroll
        for (int nt = 0; nt < 4; ++nt) vals[nt] = acc[nt][r];
        float outv[4];
        if (rope) {
            const float sf = (float)(m & (S_LEN - 1));
#pragma unroll
            for (int nt = 0; nt < 4; ++nt) {
                const int d = nt * 16 + l16;
                const float inv = exp2f(-(float)(d & 31) * 0.4152410118609203f);
                const float th = sf * inv;
                float sn, cs;
                sincosf(th, &sn, &cs);
                const float part = vals[nt ^ 2];
                const float rot = (nt < 2) ? -part : part;
                outv[nt] = vals[nt] * cs + rot * sn;
            }
        } else {
#pragma unroll
            for (int nt = 0; nt < 4; ++nt) outv[nt] = vals[nt];
        }
        const size_t crow = (size_t)m * N + n0;
        if (of32) {
            float* cp = (float*)Cp + crow;
#pragma unroll
            for (int nt = 0; nt < 4; ++nt) cp[nt * 16 + l16] = outv[nt];
        } else {
            unsigned short* cp = (unsigned short*)Cp + crow;
#pragma unroll
            for (int nt = 0; nt < 4; ++nt) cp[nt * 16 + l16] = f2bf(outv[nt]);
        }
    }
}

__global__ __launch_bounds__(256) void attn_kernel(const unsigned short* __restrict__ Q,
                                                   const unsigned short* __restrict__ Kb,
                                                   const unsigned short* __restrict__ Vb,
                                                   unsigned short* __restrict__ O, int kvs) {
    __shared__ unsigned short lp[4][16][32];

    const int wave = threadIdx.x >> 6;
    const int lane = threadIdx.x & 63;
    const int l16  = lane & 15;
    const int quad = lane >> 4;

    const int bid = blockIdx.x;
    const int qb  = bid & 31;
    const int h   = (bid >> 5) & 31;
    const int b   = bid >> 10;
    const int kvh = h >> 2;
    const int q0  = qb * 64 + wave * 16;

    const unsigned short* qbase = Q + (size_t)b * S_LEN * D_MODEL + h * HEAD_DIM;
    const unsigned short* kbase = Kb + (size_t)b * S_LEN * kvs + kvh * HEAD_DIM;
    const unsigned short* vbase = Vb + (size_t)b * S_LEN * kvs + kvh * HEAD_DIM;

    bf16x8 aq0 = *reinterpret_cast<const bf16x8*>(qbase + (size_t)(q0 + l16) * D_MODEL + quad * 8);
    bf16x8 aq1 = *reinterpret_cast<const bf16x8*>(qbase + (size_t)(q0 + l16) * D_MODEL + 32 + quad * 8);

    f32x4 o[4];
#pragma unroll
    for (int i = 0; i < 4; ++i) o[i] = (f32x4){0.f, 0.f, 0.f, 0.f};
    float mrow[4], lrow[4];
#pragma unroll
    for (int r = 0; r < 4; ++r) { mrow[r] = -3.0e38f; lrow[r] = 0.f; }

    const int kv_hi = qb * 64 + 64;
    for (int k0 = 0; k0 < kv_hi; k0 += 32) {
        f32x4 sc[2];
#pragma unroll
        for (int t = 0; t < 2; ++t) {
            const unsigned short* krow = kbase + (size_t)(k0 + t * 16 + l16) * kvs;
            bf16x8 b0 = *reinterpret_cast<const bf16x8*>(krow + quad * 8);
            bf16x8 b1 = *reinterpret_cast<const bf16x8*>(krow + 32 + quad * 8);
            f32x4 c = (f32x4){0.f, 0.f, 0.f, 0.f};
            c = MFMA16(aq0, b0, c);
            c = MFMA16(aq1, b1, c);
            sc[t] = c;
        }

        float alpha[4], p0v[4], p1v[4];
#pragma unroll
        for (int r = 0; r < 4; ++r) {
            const int qi = q0 + quad * 4 + r;
            float s0 = sc[0][r] * 0.125f;
            float s1 = sc[1][r] * 0.125f;
            if (k0 + l16 > qi)       s0 = -1.0e30f;
            if (k0 + 16 + l16 > qi)  s1 = -1.0e30f;
            float mt = fmaxf(s0, s1);
#pragma unroll
            for (int off = 1; off < 16; off <<= 1) mt = fmaxf(mt, __shfl_xor(mt, off, 64));
            const float mn = fmaxf(mrow[r], mt);
            const float al = __expf(mrow[r] - mn);
            const float p0 = __expf(s0 - mn);
            const float p1 = __expf(s1 - mn);
            float rs = p0 + p1;
#pragma unroll
            for (int off = 1; off < 16; off <<= 1) rs += __shfl_xor(rs, off, 64);
            lrow[r] = lrow[r] * al + rs;
            mrow[r] = mn;
            alpha[r] = al;
            p0v[r] = p0; p1v[r] = p1;
        }
#pragma unroll
        for (int nt = 0; nt < 4; ++nt)
#pragma unroll
            for (int r = 0; r < 4; ++r) o[nt][r] *= alpha[r];

        __syncthreads();
#pragma unroll
        for (int r = 0; r < 4; ++r) {
            lp[wave][quad * 4 + r][l16]      = f2bf(p0v[r]);
            lp[wave][quad * 4 + r][16 + l16] = f2bf(p1v[r]);
        }
        __syncthreads();
        bf16x8 ap = *reinterpret_cast<const bf16x8*>(&lp[wave][l16][quad * 8]);

#pragma unroll
        for (int nt = 0; nt < 4; ++nt) {
            const unsigned short* vcol = vbase + nt * 16 + l16 + (size_t)(k0 + quad * 8) * kvs;
            bf16x8 bv;
#pragma unroll
            for (int j = 0; j < 8; ++j) bv[j] = (short)vcol[(size_t)j * kvs];
            o[nt] = MFMA16(ap, bv, o[nt]);
        }
    }

    unsigned short* obase = O + (size_t)b * S_LEN * D_MODEL + h * HEAD_DIM;
#pragma unroll
    for (int r = 0; r < 4; ++r) {
        const float inv_l = 1.0f / lrow[r];
        unsigned short* orow = obase + (size_t)(q0 + quad * 4 + r) * D_MODEL;
#pragma unroll
        for (int nt = 0; nt < 4; ++nt)
            orow[nt * 16 + l16] = f2bf(o[nt][r] * inv_l);
    }
}

extern "C" void kernel_launch(void* const* d_in, const int* in_sizes, int n_in,
                              void* d_out, int out_size, void* d_ws, size_t ws_size,
                              hipStream_t stream) {
    const void* hidden = d_in[0];
    const void* Wq = d_in[1];
    const void* Wk = d_in[2];
    const void* Wv = d_in[3];
    const void* Wo = d_in[4];
    // d_in[5] = attention_mask: pure causal -1e9 -> implemented directly.

    char* ws = (char*)d_ws;
    int* flag = (int*)ws;
    dim3 blk(256);

    detect_dtype<<<1, blk, 0, stream>>>((const unsigned short*)hidden, flag);

    // kv 8MB + abuf 16MB + hbuf 16MB + wq 8MB + wkv 4MB + wo 8MB + vt 4MB
    const size_t NEED = 1024 + ((size_t)64 << 20);
    if (ws_size >= NEED) {
        unsigned short* kvbuf = (unsigned short*)(ws + 1024);      // [4096,1024]: K cols 0-511, V cols 512-1023
        unsigned short* abuf  = kvbuf + (size_t)4096 * 1024;       // [4096,2048]
        unsigned short* hbuf  = abuf + (size_t)4096 * 2048;        // hidden bf16
        unsigned short* wqb   = hbuf + (size_t)4096 * 2048;        // [2048,2048]
        unsigned short* wkvb  = wqb + (size_t)2048 * 2048;         // [1024,2048]: Wk | Wv
        unsigned short* wob   = wkvb + (size_t)1024 * 2048;        // [2048,2048]
        unsigned short* vtbuf = wob + (size_t)2048 * 2048;         // [2,512,2048] V^T
        unsigned short* qbuf  = (unsigned short*)d_out;            // Q bf16 lives in d_out

        cvt_all<<<dim3(2048), blk, 0, stream>>>(hidden, Wq, Wk, Wv, Wo,
                                                hbuf, wqb, wkvb, wob, flag);

        gemm_bt_lds<<<dim3(32, 16), blk, 0, stream>>>(hbuf, wqb, qbuf, 2048, flag, 1, 0);
        gemm_bt_lds<<<dim3(32, 8),  blk, 0, stream>>>(hbuf, wkvb, kvbuf, 1024, flag, 2, 0);
        transpose_v<<<dim3(512), blk, 0, stream>>>(kvbuf + 512, vtbuf);
        attn_kernel4<<<dim3(2 * NHEAD * (S_LEN / 256)), blk, 0, stream>>>(qbuf, kvbuf, vtbuf, abuf, 1024);
        gemm_bt_lds<<<dim3(32, 16), blk, 0, stream>>>(abuf, wob, d_out, 2048, flag, 0, 1);
    } else {
        // legacy 24MB path
        unsigned short* kbuf = (unsigned short*)(ws + 1024);
        unsigned short* vbuf = (unsigned short*)(ws + 1024 + (4u << 20));
        unsigned short* abuf = (unsigned short*)(ws + 1024 + (8u << 20));
        unsigned short* qbuf = (unsigned short*)d_out;
        gemm_bt<<<dim3(M_ROWS / 64, D_MODEL / 64), blk, 0, stream>>>(hidden, Wq, qbuf, D_MODEL, flag, 1, 1, 0);
        gemm_bt<<<dim3(M_ROWS / 64, (NKVH * HEAD_DIM) / 64), blk, 0, stream>>>(hidden, Wk, kbuf, NKVH * HEAD_DIM, flag, 1, 1, 0);
        gemm_bt<<<dim3(M_ROWS / 64, (NKVH * HEAD_DIM) / 64), blk, 0, stream>>>(hidden, Wv, vbuf, NKVH * HEAD_DIM, flag, 1, 0, 0);
        attn_kernel<<<dim3(2 * NHEAD * (S_LEN / 64)), blk, 0, stream>>>(qbuf, kbuf, vbuf, abuf, 512);
        gemm_bt<<<dim3(M_ROWS / 64, D_MODEL / 64), blk, 0, stream>>>(abuf, Wo, d_out, D_MODEL, flag, 0, 0, 1);
    }
}

// Round 6
// 428.152 us; speedup vs baseline: 4.4045x; 1.0398x over previous
//
#include <hip/hip_runtime.h>

// FlashAttentionWrapper: B=2, S=2048, D=2048, NH=32, HD=64, NKV=8, NREP=4,
// causal, RoPE theta=1e4. Input dtype (bf16/f32) detected at runtime.
// New-path workspace (64MB+1KB):
//   [flag 4B pad 1KB][kvbuf 4096x1024 8MB][abuf 4096x2048 16MB]
//   [hbuf 16MB][wqb 8MB][wkvb 4MB][wob 8MB][vtbuf 2x512x2048 4MB]
// wqb+wkvb are CONTIGUOUS => one [3072,2048] QKV weight matrix (fused GEMM).
// Q-projection result lives in d_out (dead before O-proj overwrites it).
// Fallback path (ws < 64MB+1KB): original direct-load kernels, 24MB+1KB.
//
// NOTE (round-5 lesson): v_cvt_pk_bf16_f32 inline-asm P-store caused absmax
// 3.6 failure (suspected lo/hi pack-order mismatch). P-store uses f2bf.

#define S_LEN 2048
#define D_MODEL 2048
#define NHEAD 32
#define HEAD_DIM 64
#define NKVH 8
#define M_ROWS 4096   // B*S
#define KVW (NKVH * HEAD_DIM)   // 512

typedef __attribute__((ext_vector_type(4))) float f32x4;
typedef __attribute__((ext_vector_type(8))) short bf16x8;

#define MFMA16(a, b, c) __builtin_amdgcn_mfma_f32_16x16x32_bf16((a), (b), (c), 0, 0, 0)

// async global->LDS, 16B per lane; LDS dest is wave-uniform base + lane*16
#define GLOAD_LDS16(g, l)                                                     \
    __builtin_amdgcn_global_load_lds(                                         \
        (const __attribute__((address_space(1))) void*)(g),                   \
        (__attribute__((address_space(3))) void*)(l), 16, 0, 0)

static __device__ __forceinline__ unsigned short f2bf(float f) {
    union { float f; unsigned int i; } v; v.f = f;
    unsigned int x = v.i;
    unsigned int r = (x + 0x7fffu + ((x >> 16) & 1u)) >> 16;  // RNE
    return (unsigned short)r;
}

static __device__ __forceinline__ float fexp2(float x) {
#if __has_builtin(__builtin_amdgcn_exp2f)
    return __builtin_amdgcn_exp2f(x);
#else
    return exp2f(x);
#endif
}

// ---------------------------------------------------------------------------
// Dtype detection: f32 data read as uint16 shows impossible bf16 exponents at
// even indices.
// ---------------------------------------------------------------------------
__global__ __launch_bounds__(256) void detect_dtype(const unsigned short* __restrict__ h,
                                                    int* __restrict__ flag) {
    __shared__ int cnt;
    if (threadIdx.x == 0) cnt = 0;
    __syncthreads();
    const unsigned short v = h[2 * threadIdx.x];
    const int e = (v >> 7) & 0xFF;
    if (e >= 0x8D) atomicAdd(&cnt, 1);
    __syncthreads();
    if (threadIdx.x == 0) *flag = (cnt >= 8) ? 1 : 0;
}

static __device__ __forceinline__ bf16x8 load_frag(bool f32p, const void* p, size_t off) {
    if (f32p) {
        const float* fp = (const float*)p + off;
        f32x4 x = *reinterpret_cast<const f32x4*>(fp);
        f32x4 y = *reinterpret_cast<const f32x4*>(fp + 4);
        bf16x8 r;
        r[0] = (short)f2bf(x[0]); r[1] = (short)f2bf(x[1]);
        r[2] = (short)f2bf(x[2]); r[3] = (short)f2bf(x[3]);
        r[4] = (short)f2bf(y[0]); r[5] = (short)f2bf(y[1]);
        r[6] = (short)f2bf(y[2]); r[7] = (short)f2bf(y[3]);
        return r;
    }
    return *reinterpret_cast<const bf16x8*>((const unsigned short*)p + off);
}

// ---------------------------------------------------------------------------
// Fused one-time f32->bf16 conversion (or bf16 copy) of all 5 operands.
// ---------------------------------------------------------------------------
__global__ __launch_bounds__(256) void cvt_all(const void* __restrict__ h,
                                               const void* __restrict__ wq,
                                               const void* __restrict__ wk,
                                               const void* __restrict__ wv,
                                               const void* __restrict__ wo,
                                               unsigned short* __restrict__ hbuf,
                                               unsigned short* __restrict__ wqb,
                                               unsigned short* __restrict__ wkvb,
                                               unsigned short* __restrict__ wob,
                                               const int* __restrict__ flag) {
    const bool f32p = (*flag != 0);
    const int e0 = 1048576;            // hidden 4096x2048
    const int e1 = e0 + 524288;        // Wq 2048x2048
    const int e2 = e1 + 131072;        // Wk 512x2048
    const int e3 = e2 + 131072;        // Wv 512x2048
    const int e4 = e3 + 524288;        // Wo 2048x2048
    int i = blockIdx.x * 256 + threadIdx.x;
    const int stride = gridDim.x * 256;
    for (; i < e4; i += stride) {
        const void* s;
        unsigned short* d;
        size_t off;
        if (i < e0)      { s = h;  d = hbuf; off = (size_t)i; }
        else if (i < e1) { s = wq; d = wqb;  off = (size_t)(i - e0); }
        else if (i < e2) { s = wk; d = wkvb; off = (size_t)(i - e1); }
        else if (i < e3) { s = wv; d = wkvb + (size_t)512 * 2048; off = (size_t)(i - e2); }
        else             { s = wo; d = wob;  off = (size_t)(i - e3); }
        bf16x8 v = load_frag(f32p, s, off * 8);
        *reinterpret_cast<bf16x8*>(d + off * 8) = v;
    }
}

// ---------------------------------------------------------------------------
// RoPE epilogue helper (d = column mod 64).
// ---------------------------------------------------------------------------
static __device__ __forceinline__ void rope4(const float (&vals)[4], float (&outv)[4],
                                             int m, int l16) {
    const float sf = (float)(m & (S_LEN - 1));
#pragma unroll
    for (int nt = 0; nt < 4; ++nt) {
        const int d = nt * 16 + l16;
        const float inv = exp2f(-(float)(d & 31) * 0.4152410118609203f);
        const float th = sf * inv;
        float sn, cs;
        sincosf(th, &sn, &cs);
        const float part = vals[nt ^ 2];
        const float rot = (nt < 2) ? -part : part;  // d<32: -x2 ; d>=32: +x1
        outv[nt] = vals[nt] * cs + rot * sn;
    }
}

// ---------------------------------------------------------------------------
// Fused QKV GEMM (m97 structure): A[4096,2048] @ Wqkv[3072,2048]^T, all bf16.
// 128x128 tile, BK=32, 4 waves 2x2, global_load_lds width=16. Epilogue routes
// each wave's head-aligned 64-col span: cols<2048 -> Q (d_out, stride 2048,
// RoPE); 2048..2559 -> K half of kvbuf (stride 1024, RoPE); >=2560 -> V half
// (no RoPE).
// ---------------------------------------------------------------------------
__global__ __launch_bounds__(256) void gemm_qkv_lds(const unsigned short* __restrict__ A,
                                                    const unsigned short* __restrict__ W,
                                                    unsigned short* __restrict__ Qo,
                                                    unsigned short* __restrict__ KVo) {
    __shared__ unsigned short lds_a[128 * 32];   // 8KB
    __shared__ unsigned short lds_b[128 * 32];   // 8KB

    const int wave = threadIdx.x >> 6;
    const int lane = threadIdx.x & 63;
    const int l16  = lane & 15;
    const int quad = lane >> 4;
    const int wm   = wave >> 1;
    const int wn   = wave & 1;

    const int m0 = blockIdx.x * 128;
    const int n0 = blockIdx.y * 128;

    const int srow = lane >> 2;
    const int scol = (lane & 3) * 8;
    const unsigned short* ag[2];
    const unsigned short* wg[2];
#pragma unroll
    for (int i = 0; i < 2; ++i) {
        const int c = wave * 2 + i;
        ag[i] = A + (size_t)(m0 + c * 16 + srow) * D_MODEL + scol;
        wg[i] = W + (size_t)(n0 + c * 16 + srow) * D_MODEL + scol;
    }

    f32x4 acc[4][4];
#pragma unroll
    for (int i = 0; i < 4; ++i)
#pragma unroll
        for (int j = 0; j < 4; ++j) acc[i][j] = (f32x4){0.f, 0.f, 0.f, 0.f};

    for (int k0 = 0; k0 < D_MODEL; k0 += 32) {
#pragma unroll
        for (int i = 0; i < 2; ++i) {
            const int c = wave * 2 + i;
            GLOAD_LDS16(ag[i] + k0, &lds_a[c * 512]);
            GLOAD_LDS16(wg[i] + k0, &lds_b[c * 512]);
        }
        __syncthreads();

        bf16x8 af[4], bfm[4];
#pragma unroll
        for (int t = 0; t < 4; ++t) {
            af[t]  = *reinterpret_cast<const bf16x8*>(&lds_a[(wm * 64 + t * 16 + l16) * 32 + quad * 8]);
            bfm[t] = *reinterpret_cast<const bf16x8*>(&lds_b[(wn * 64 + t * 16 + l16) * 32 + quad * 8]);
        }
#pragma unroll
        for (int mt = 0; mt < 4; ++mt)
#pragma unroll
            for (int nt = 0; nt < 4; ++nt)
                acc[mt][nt] = MFMA16(af[mt], bfm[nt], acc[mt][nt]);
        __syncthreads();
    }

    const int ncol0 = n0 + wn * 64;                 // wave-uniform, head-aligned
    const bool do_rope = (ncol0 < 2048 + KVW);      // Q and K regions
    unsigned short* dst;
    int cstride, c0;
    if (ncol0 < 2048) { dst = Qo;  cstride = 2048; c0 = ncol0; }
    else              { dst = KVo; cstride = 1024; c0 = ncol0 - 2048; }

#pragma unroll
    for (int mt = 0; mt < 4; ++mt) {
#pragma unroll
        for (int r = 0; r < 4; ++r) {
            const int m = m0 + wm * 64 + mt * 16 + quad * 4 + r;
            float vals[4];
#pragma unroll
            for (int nt = 0; nt < 4; ++nt) vals[nt] = acc[mt][nt][r];
            float outv[4];
            if (do_rope) {
                rope4(vals, outv, m, l16);
            } else {
#pragma unroll
                for (int nt = 0; nt < 4; ++nt) outv[nt] = vals[nt];
            }
            unsigned short* cp = dst + (size_t)m * cstride + c0;
#pragma unroll
            for (int nt = 0; nt < 4; ++nt) cp[nt * 16 + l16] = f2bf(outv[nt]);
        }
    }
}

// ---------------------------------------------------------------------------
// LDS-staged GEMM (m97 structure): C[M,N] = A[M,2048] @ W[N,2048]^T, all bf16.
// Used for the O-projection (rope=0). finalout!=0 && *flag!=0 -> f32 output.
// ---------------------------------------------------------------------------
__global__ __launch_bounds__(256) void gemm_bt_lds(const unsigned short* __restrict__ A,
                                                   const unsigned short* __restrict__ W,
                                                   void* __restrict__ Cp, int N,
                                                   const int* __restrict__ flag,
                                                   int rope, int finalout) {
    __shared__ unsigned short lds_a[128 * 32];
    __shared__ unsigned short lds_b[128 * 32];

    const int wave = threadIdx.x >> 6;
    const int lane = threadIdx.x & 63;
    const int l16  = lane & 15;
    const int quad = lane >> 4;
    const int wm   = wave >> 1;
    const int wn   = wave & 1;

    const int m0 = blockIdx.x * 128;
    const int n0 = blockIdx.y * 128;

    const int srow = lane >> 2;
    const int scol = (lane & 3) * 8;
    const unsigned short* ag[2];
    const unsigned short* wg[2];
#pragma unroll
    for (int i = 0; i < 2; ++i) {
        const int c = wave * 2 + i;
        ag[i] = A + (size_t)(m0 + c * 16 + srow) * D_MODEL + scol;
        wg[i] = W + (size_t)(n0 + c * 16 + srow) * D_MODEL + scol;
    }

    f32x4 acc[4][4];
#pragma unroll
    for (int i = 0; i < 4; ++i)
#pragma unroll
        for (int j = 0; j < 4; ++j) acc[i][j] = (f32x4){0.f, 0.f, 0.f, 0.f};

    for (int k0 = 0; k0 < D_MODEL; k0 += 32) {
#pragma unroll
        for (int i = 0; i < 2; ++i) {
            const int c = wave * 2 + i;
            GLOAD_LDS16(ag[i] + k0, &lds_a[c * 512]);
            GLOAD_LDS16(wg[i] + k0, &lds_b[c * 512]);
        }
        __syncthreads();

        bf16x8 af[4], bfm[4];
#pragma unroll
        for (int t = 0; t < 4; ++t) {
            af[t]  = *reinterpret_cast<const bf16x8*>(&lds_a[(wm * 64 + t * 16 + l16) * 32 + quad * 8]);
            bfm[t] = *reinterpret_cast<const bf16x8*>(&lds_b[(wn * 64 + t * 16 + l16) * 32 + quad * 8]);
        }
#pragma unroll
        for (int mt = 0; mt < 4; ++mt)
#pragma unroll
            for (int nt = 0; nt < 4; ++nt)
                acc[mt][nt] = MFMA16(af[mt], bfm[nt], acc[mt][nt]);
        __syncthreads();
    }

    const bool isf32 = (*flag != 0);
    const bool of32  = isf32 && (finalout != 0);
    const bool do_rope = (rope != 0);
    const int ncol0 = n0 + wn * 64;

#pragma unroll
    for (int mt = 0; mt < 4; ++mt) {
#pragma unroll
        for (int r = 0; r < 4; ++r) {
            const int m = m0 + wm * 64 + mt * 16 + quad * 4 + r;
            float vals[4];
#pragma unroll
            for (int nt = 0; nt < 4; ++nt) vals[nt] = acc[mt][nt][r];
            float outv[4];
            if (do_rope) {
                rope4(vals, outv, m, l16);
            } else {
#pragma unroll
                for (int nt = 0; nt < 4; ++nt) outv[nt] = vals[nt];
            }
            const size_t crow = (size_t)m * N + ncol0;
            if (of32) {
                float* cp = (float*)Cp + crow;
#pragma unroll
                for (int nt = 0; nt < 4; ++nt) cp[nt * 16 + l16] = outv[nt];
            } else {
                unsigned short* cp = (unsigned short*)Cp + crow;
#pragma unroll
                for (int nt = 0; nt < 4; ++nt) cp[nt * 16 + l16] = f2bf(outv[nt]);
            }
        }
    }
}

// ---------------------------------------------------------------------------
// V transpose: Vsrc = kvbuf V-half [B*S rows, stride 1024] cols 0..511
//   -> Vt[b][c][s] ([B][512][S]).  64x64 LDS tiles, fully coalesced.
// ---------------------------------------------------------------------------
__global__ __launch_bounds__(256) void transpose_v(const unsigned short* __restrict__ Vsrc,
                                                   unsigned short* __restrict__ Vt) {
    __shared__ unsigned short t[64][72];
    const int bid = blockIdx.x;
    const int ct = bid & 7;
    const int st = (bid >> 3) & 31;
    const int b  = bid >> 8;
    const unsigned short* src = Vsrc + ((size_t)b * S_LEN + st * 64) * 1024 + ct * 64;
    unsigned short* dst = Vt + ((size_t)b * KVW + ct * 64) * S_LEN + st * 64;
    const int r0 = threadIdx.x >> 3;
    const int c0 = (threadIdx.x & 7) * 8;
#pragma unroll
    for (int h = 0; h < 2; ++h) {
        bf16x8 v = *reinterpret_cast<const bf16x8*>(src + (size_t)(r0 + h * 32) * 1024 + c0);
        *reinterpret_cast<bf16x8*>(&t[r0 + h * 32][c0]) = v;
    }
    __syncthreads();
#pragma unroll
    for (int h = 0; h < 2; ++h) {
        const int cr = r0 + h * 32;
        bf16x8 v;
#pragma unroll
        for (int j = 0; j < 8; ++j) v[j] = (short)t[c0 + j][cr];
        *reinterpret_cast<bf16x8*>(dst + (size_t)cr * S_LEN + c0) = v;
    }
}

// ---------------------------------------------------------------------------
// Flash attention v4 (round-4 verified): causal, GQA. 4 independent waves per
// block, 32 q-rows/wave, 64-key tiles, causal-paired q-tiles (qt, 15-qt).
// Softmax in log2 domain with DEFERRED max (THR=8, wave-uniform __any) and
// row-sum via MFMA (l = P @ ones). P-store via f2bf (verified path).
// ---------------------------------------------------------------------------
struct AttnCtx {
    const unsigned short* qbase;
    const unsigned short* kbase;
    const unsigned short* vtbase;
    unsigned short* obase;
    int kvs;
    int l16, quad;
    unsigned short (*lpw)[72];   // [32][72] per-wave slice
};

#define SM_C 0.18033688011112042f   // 0.125 * log2(e)
#define SM_THR 8.0f

static __device__ __forceinline__ void attn_qtile(const AttnCtx& cx, int q0w) {
    const int l16 = cx.l16, quad = cx.quad;
    const int kvs = cx.kvs;

    bf16x8 ones;
#pragma unroll
    for (int j = 0; j < 8; ++j) ones[j] = (short)0x3F80;   // bf16 1.0

    bf16x8 aq[2][2];
#pragma unroll
    for (int m = 0; m < 2; ++m)
#pragma unroll
        for (int kh = 0; kh < 2; ++kh)
            aq[m][kh] = *reinterpret_cast<const bf16x8*>(
                cx.qbase + (size_t)(q0w + m * 16 + l16) * D_MODEL + kh * 32 + quad * 8);

    f32x4 o[2][4];
    f32x4 c_l[2];     // row-sum accumulator (l = P @ ones)
#pragma unroll
    for (int m = 0; m < 2; ++m) {
#pragma unroll
        for (int i = 0; i < 4; ++i) o[m][i] = (f32x4){0.f, 0.f, 0.f, 0.f};
        c_l[m] = (f32x4){0.f, 0.f, 0.f, 0.f};
    }
    float m2[2][4];   // running max, log2 domain
#pragma unroll
    for (int m = 0; m < 2; ++m)
#pragma unroll
        for (int r = 0; r < 4; ++r) m2[m][r] = 0.f;

    const int kv_hi = q0w + 32;   // per-wave causal bound

    bf16x8 kfa[8], kfb[8];        // K frags [t*2+kh], double-buffered

#define LOADK(DST, KK0)                                                       \
    {                                                                         \
        _Pragma("unroll")                                                     \
        for (int t = 0; t < 4; ++t) {                                         \
            const unsigned short* krow =                                      \
                cx.kbase + (size_t)((KK0) + t * 16 + l16) * kvs;              \
            DST[2 * t]     = *reinterpret_cast<const bf16x8*>(krow + quad * 8);       \
            DST[2 * t + 1] = *reinterpret_cast<const bf16x8*>(krow + 32 + quad * 8);  \
        }                                                                     \
    }

#define ATTN_BODY(CUR, NXT)                                                   \
    {                                                                         \
        f32x4 sc[2][4];                                                       \
        __builtin_amdgcn_s_setprio(1);                                        \
        _Pragma("unroll")                                                     \
        for (int t = 0; t < 4; ++t) {                                         \
            _Pragma("unroll")                                                 \
            for (int m = 0; m < 2; ++m) {                                     \
                f32x4 c = (f32x4){0.f, 0.f, 0.f, 0.f};                        \
                c = MFMA16(aq[m][0], CUR[2 * t], c);                          \
                c = MFMA16(aq[m][1], CUR[2 * t + 1], c);                      \
                sc[m][t] = c;                                                 \
            }                                                                 \
        }                                                                     \
        __builtin_amdgcn_s_setprio(0);                                        \
        if (k0 + 64 < kv_hi) LOADK(NXT, k0 + 64);                             \
        bf16x8 vf[8];                                                         \
        _Pragma("unroll")                                                     \
        for (int nt = 0; nt < 4; ++nt) {                                      \
            const unsigned short* vrow =                                      \
                cx.vtbase + (size_t)(nt * 16 + l16) * S_LEN + k0 + quad * 8;  \
            vf[2 * nt]     = *reinterpret_cast<const bf16x8*>(vrow);          \
            vf[2 * nt + 1] = *reinterpret_cast<const bf16x8*>(vrow + 32);     \
        }                                                                     \
        const bool full = (k0 + 63 <= q0w);                                   \
        float pm[2][4];                                                       \
        float dif = -3.0e38f;                                                 \
        _Pragma("unroll")                                                     \
        for (int m = 0; m < 2; ++m) {                                         \
            _Pragma("unroll")                                                 \
            for (int r = 0; r < 4; ++r) {                                     \
                const int qi = q0w + m * 16 + quad * 4 + r;                   \
                float s[4];                                                   \
                _Pragma("unroll")                                             \
                for (int t = 0; t < 4; ++t) {                                 \
                    s[t] = sc[m][t][r] * SM_C;                                \
                    if (!full && (k0 + t * 16 + l16 > qi)) s[t] = -1.0e30f;   \
                    sc[m][t][r] = s[t];                                       \
                }                                                             \
                const float p = fmaxf(fmaxf(s[0], s[1]), fmaxf(s[2], s[3])); \
                pm[m][r] = p;                                                 \
                dif = fmaxf(dif, p - m2[m][r]);                               \
            }                                                                 \
        }                                                                     \
        if (__any(dif > SM_THR)) {                                            \
            _Pragma("unroll")                                                 \
            for (int m = 0; m < 2; ++m) {                                     \
                _Pragma("unroll")                                             \
                for (int r = 0; r < 4; ++r) {                                 \
                    float mt = pm[m][r];                                      \
                    _Pragma("unroll")                                         \
                    for (int off = 1; off < 16; off <<= 1)                    \
                        mt = fmaxf(mt, __shfl_xor(mt, off, 64));              \
                    const float mn = fmaxf(m2[m][r], mt);                     \
                    const float al = fexp2(m2[m][r] - mn);                    \
                    m2[m][r] = mn;                                            \
                    _Pragma("unroll")                                         \
                    for (int nt = 0; nt < 4; ++nt) o[m][nt][r] *= al;         \
                    c_l[m][r] *= al;                                          \
                }                                                             \
            }                                                                 \
        }                                                                     \
        /* pass 2: p = 2^(s - m2), write P tile (f2bf — verified) */          \
        _Pragma("unroll")                                                     \
        for (int m = 0; m < 2; ++m) {                                         \
            _Pragma("unroll")                                                 \
            for (int r = 0; r < 4; ++r) {                                     \
                const float mb = m2[m][r];                                    \
                _Pragma("unroll")                                             \
                for (int t = 0; t < 4; ++t) {                                 \
                    const float pv = fexp2(sc[m][t][r] - mb);                 \
                    cx.lpw[m * 16 + quad * 4 + r][t * 16 + l16] = f2bf(pv);   \
                }                                                             \
            }                                                                 \
        }                                                                     \
        asm volatile("" ::: "memory");                                        \
        bf16x8 ap[2][2];                                                      \
        _Pragma("unroll")                                                     \
        for (int m = 0; m < 2; ++m)                                           \
            _Pragma("unroll")                                                 \
            for (int kh = 0; kh < 2; ++kh)                                    \
                ap[m][kh] = *reinterpret_cast<const bf16x8*>(                 \
                    &cx.lpw[m * 16 + l16][kh * 32 + quad * 8]);               \
        __builtin_amdgcn_s_setprio(1);                                        \
        _Pragma("unroll")                                                     \
        for (int nt = 0; nt < 4; ++nt)                                        \
            _Pragma("unroll")                                                 \
            for (int m = 0; m < 2; ++m) {                                     \
                o[m][nt] = MFMA16(ap[m][0], vf[2 * nt], o[m][nt]);            \
                o[m][nt] = MFMA16(ap[m][1], vf[2 * nt + 1], o[m][nt]);        \
            }                                                                 \
        _Pragma("unroll")                                                     \
        for (int m = 0; m < 2; ++m) {                                         \
            c_l[m] = MFMA16(ap[m][0], ones, c_l[m]);                          \
            c_l[m] = MFMA16(ap[m][1], ones, c_l[m]);                          \
        }                                                                     \
        __builtin_amdgcn_s_setprio(0);                                        \
    }

    LOADK(kfa, 0);
    int k0 = 0;
    for (;;) {
        ATTN_BODY(kfa, kfb);
        k0 += 64;
        if (k0 >= kv_hi) break;
        ATTN_BODY(kfb, kfa);
        k0 += 64;
        if (k0 >= kv_hi) break;
    }
#undef ATTN_BODY
#undef LOADK

#pragma unroll
    for (int m = 0; m < 2; ++m)
#pragma unroll
        for (int r = 0; r < 4; ++r) {
            const float inv_l = 1.0f / c_l[m][r];
            unsigned short* orow = cx.obase + (size_t)(q0w + m * 16 + quad * 4 + r) * D_MODEL;
#pragma unroll
            for (int nt = 0; nt < 4; ++nt)
                orow[nt * 16 + l16] = f2bf(o[m][nt][r] * inv_l);
        }
}

__global__ __launch_bounds__(256) void attn_kernel4(const unsigned short* __restrict__ Q,
                                                    const unsigned short* __restrict__ Kb,
                                                    const unsigned short* __restrict__ Vt,
                                                    unsigned short* __restrict__ O, int kvs) {
    __shared__ unsigned short lp[4][32][72];   // per-wave P (32 q x 64 k), padded

    const int wave = threadIdx.x >> 6;
    const int lane = threadIdx.x & 63;

    const int bid = blockIdx.x;
    const int p   = bid & 7;                    // pair index: q-tiles p and 15-p
    const int h   = (bid >> 3) & (NHEAD - 1);
    const int b   = bid >> 8;
    const int kvh = h >> 2;

    AttnCtx cx;
    cx.qbase  = Q + (size_t)b * S_LEN * D_MODEL + h * HEAD_DIM;
    cx.kbase  = Kb + (size_t)b * S_LEN * kvs + kvh * HEAD_DIM;
    cx.vtbase = Vt + ((size_t)b * KVW + kvh * HEAD_DIM) * S_LEN;
    cx.obase  = O + (size_t)b * S_LEN * D_MODEL + h * HEAD_DIM;
    cx.kvs    = kvs;
    cx.l16    = lane & 15;
    cx.quad   = lane >> 4;
    cx.lpw    = lp[wave];

    attn_qtile(cx, p * 128 + wave * 32);                 // light tile
    attn_qtile(cx, (15 - p) * 128 + wave * 32);          // heavy tile
}

// ---------------------------------------------------------------------------
// Legacy direct-load GEMM + attention (fallback path only).
// ---------------------------------------------------------------------------
__global__ __launch_bounds__(256) void gemm_bt(const void* __restrict__ Ap,
                                               const void* __restrict__ Wp,
                                               void* __restrict__ Cp, int N,
                                               const int* __restrict__ flag,
                                               int a_input, int rope, int finalout) {
    const bool isf32 = (*flag != 0);
    const bool af32 = isf32 && (a_input != 0);
    const bool wf32 = isf32;
    const bool of32 = isf32 && (finalout != 0);

    const int wave = threadIdx.x >> 6;
    const int lane = threadIdx.x & 63;
    const int l16  = lane & 15;
    const int quad = lane >> 4;
    const int m0 = blockIdx.x * 64 + wave * 16;
    const int n0 = blockIdx.y * 64;

    f32x4 acc[4];
#pragma unroll
    for (int i = 0; i < 4; ++i) acc[i] = (f32x4){0.f, 0.f, 0.f, 0.f};

    const size_t aoff = (size_t)(m0 + l16) * D_MODEL + quad * 8;
    size_t woff[4];
#pragma unroll
    for (int nt = 0; nt < 4; ++nt)
        woff[nt] = (size_t)(n0 + nt * 16 + l16) * D_MODEL + quad * 8;

    for (int k0 = 0; k0 < D_MODEL; k0 += 32) {
        bf16x8 a = load_frag(af32, Ap, aoff + k0);
#pragma unroll
        for (int nt = 0; nt < 4; ++nt) {
            bf16x8 b = load_frag(wf32, Wp, woff[nt] + k0);
            acc[nt] = MFMA16(a, b, acc[nt]);
        }
    }

#pragma unroll
    for (int r = 0; r < 4; ++r) {
        const int m = m0 + quad * 4 + r;
        float vals[4];
#pragma unroll
        for (int nt = 0; nt < 4; ++nt) vals[nt] = acc[nt][r];
        float outv[4];
        if (rope) {
            rope4(vals, outv, m, l16);
        } else {
#pragma unroll
            for (int nt = 0; nt < 4; ++nt) outv[nt] = vals[nt];
        }
        const size_t crow = (size_t)m * N + n0;
        if (of32) {
            float* cp = (float*)Cp + crow;
#pragma unroll
            for (int nt = 0; nt < 4; ++nt) cp[nt * 16 + l16] = outv[nt];
        } else {
            unsigned short* cp = (unsigned short*)Cp + crow;
#pragma unroll
            for (int nt = 0; nt < 4; ++nt) cp[nt * 16 + l16] = f2bf(outv[nt]);
        }
    }
}

__global__ __launch_bounds__(256) void attn_kernel(const unsigned short* __restrict__ Q,
                                                   const unsigned short* __restrict__ Kb,
                                                   const unsigned short* __restrict__ Vb,
                                                   unsigned short* __restrict__ O, int kvs) {
    __shared__ unsigned short lp[4][16][32];

    const int wave = threadIdx.x >> 6;
    const int lane = threadIdx.x & 63;
    const int l16  = lane & 15;
    const int quad = lane >> 4;

    const int bid = blockIdx.x;
    const int qb  = bid & 31;
    const int h   = (bid >> 5) & 31;
    const int b   = bid >> 10;
    const int kvh = h >> 2;
    const int q0  = qb * 64 + wave * 16;

    const unsigned short* qbase = Q + (size_t)b * S_LEN * D_MODEL + h * HEAD_DIM;
    const unsigned short* kbase = Kb + (size_t)b * S_LEN * kvs + kvh * HEAD_DIM;
    const unsigned short* vbase = Vb + (size_t)b * S_LEN * kvs + kvh * HEAD_DIM;

    bf16x8 aq0 = *reinterpret_cast<const bf16x8*>(qbase + (size_t)(q0 + l16) * D_MODEL + quad * 8);
    bf16x8 aq1 = *reinterpret_cast<const bf16x8*>(qbase + (size_t)(q0 + l16) * D_MODEL + 32 + quad * 8);

    f32x4 o[4];
#pragma unroll
    for (int i = 0; i < 4; ++i) o[i] = (f32x4){0.f, 0.f, 0.f, 0.f};
    float mrow[4], lrow[4];
#pragma unroll
    for (int r = 0; r < 4; ++r) { mrow[r] = -3.0e38f; lrow[r] = 0.f; }

    const int kv_hi = qb * 64 + 64;
    for (int k0 = 0; k0 < kv_hi; k0 += 32) {
        f32x4 sc[2];
#pragma unroll
        for (int t = 0; t < 2; ++t) {
            const unsigned short* krow = kbase + (size_t)(k0 + t * 16 + l16) * kvs;
            bf16x8 b0 = *reinterpret_cast<const bf16x8*>(krow + quad * 8);
            bf16x8 b1 = *reinterpret_cast<const bf16x8*>(krow + 32 + quad * 8);
            f32x4 c = (f32x4){0.f, 0.f, 0.f, 0.f};
            c = MFMA16(aq0, b0, c);
            c = MFMA16(aq1, b1, c);
            sc[t] = c;
        }

        float alpha[4], p0v[4], p1v[4];
#pragma unroll
        for (int r = 0; r < 4; ++r) {
            const int qi = q0 + quad * 4 + r;
            float s0 = sc[0][r] * 0.125f;
            float s1 = sc[1][r] * 0.125f;
            if (k0 + l16 > qi)       s0 = -1.0e30f;
            if (k0 + 16 + l16 > qi)  s1 = -1.0e30f;
            float mt = fmaxf(s0, s1);
#pragma unroll
            for (int off = 1; off < 16; off <<= 1) mt = fmaxf(mt, __shfl_xor(mt, off, 64));
            const float mn = fmaxf(mrow[r], mt);
            const float al = __expf(mrow[r] - mn);
            const float p0 = __expf(s0 - mn);
            const float p1 = __expf(s1 - mn);
            float rs = p0 + p1;
#pragma unroll
            for (int off = 1; off < 16; off <<= 1) rs += __shfl_xor(rs, off, 64);
            lrow[r] = lrow[r] * al + rs;
            mrow[r] = mn;
            alpha[r] = al;
            p0v[r] = p0; p1v[r] = p1;
        }
#pragma unroll
        for (int nt = 0; nt < 4; ++nt)
#pragma unroll
            for (int r = 0; r < 4; ++r) o[nt][r] *= alpha[r];

        __syncthreads();
#pragma unroll
        for (int r = 0; r < 4; ++r) {
            lp[wave][quad * 4 + r][l16]      = f2bf(p0v[r]);
            lp[wave][quad * 4 + r][16 + l16] = f2bf(p1v[r]);
        }
        __syncthreads();
        bf16x8 ap = *reinterpret_cast<const bf16x8*>(&lp[wave][l16][quad * 8]);

#pragma unroll
        for (int nt = 0; nt < 4; ++nt) {
            const unsigned short* vcol = vbase + nt * 16 + l16 + (size_t)(k0 + quad * 8) * kvs;
            bf16x8 bv;
#pragma unroll
            for (int j = 0; j < 8; ++j) bv[j] = (short)vcol[(size_t)j * kvs];
            o[nt] = MFMA16(ap, bv, o[nt]);
        }
    }

    unsigned short* obase = O + (size_t)b * S_LEN * D_MODEL + h * HEAD_DIM;
#pragma unroll
    for (int r = 0; r < 4; ++r) {
        const float inv_l = 1.0f / lrow[r];
        unsigned short* orow = obase + (size_t)(q0 + quad * 4 + r) * D_MODEL;
#pragma unroll
        for (int nt = 0; nt < 4; ++nt)
            orow[nt * 16 + l16] = f2bf(o[nt][r] * inv_l);
    }
}

extern "C" void kernel_launch(void* const* d_in, const int* in_sizes, int n_in,
                              void* d_out, int out_size, void* d_ws, size_t ws_size,
                              hipStream_t stream) {
    const void* hidden = d_in[0];
    const void* Wq = d_in[1];
    const void* Wk = d_in[2];
    const void* Wv = d_in[3];
    const void* Wo = d_in[4];
    // d_in[5] = attention_mask: pure causal -1e9 -> implemented directly.

    char* ws = (char*)d_ws;
    int* flag = (int*)ws;
    dim3 blk(256);

    detect_dtype<<<1, blk, 0, stream>>>((const unsigned short*)hidden, flag);

    // kv 8MB + abuf 16MB + hbuf 16MB + wq 8MB + wkv 4MB + wo 8MB + vt 4MB
    const size_t NEED = 1024 + ((size_t)64 << 20);
    if (ws_size >= NEED) {
        unsigned short* kvbuf = (unsigned short*)(ws + 1024);      // [4096,1024]: K cols 0-511, V cols 512-1023
        unsigned short* abuf  = kvbuf + (size_t)4096 * 1024;       // [4096,2048]
        unsigned short* hbuf  = abuf + (size_t)4096 * 2048;        // hidden bf16
        unsigned short* wqb   = hbuf + (size_t)4096 * 2048;        // [2048,2048]  } contiguous =
        unsigned short* wkvb  = wqb + (size_t)2048 * 2048;         // [1024,2048]  } Wqkv [3072,2048]
        unsigned short* wob   = wkvb + (size_t)1024 * 2048;        // [2048,2048]
        unsigned short* vtbuf = wob + (size_t)2048 * 2048;         // [2,512,2048] V^T
        unsigned short* qbuf  = (unsigned short*)d_out;            // Q bf16 lives in d_out

        cvt_all<<<dim3(2048), blk, 0, stream>>>(hidden, Wq, Wk, Wv, Wo,
                                                hbuf, wqb, wkvb, wob, flag);

        gemm_qkv_lds<<<dim3(32, 24), blk, 0, stream>>>(hbuf, wqb, qbuf, kvbuf);
        transpose_v<<<dim3(512), blk, 0, stream>>>(kvbuf + 512, vtbuf);
        attn_kernel4<<<dim3(2 * NHEAD * (S_LEN / 256)), blk, 0, stream>>>(qbuf, kvbuf, vtbuf, abuf, 1024);
        gemm_bt_lds<<<dim3(32, 16), blk, 0, stream>>>(abuf, wob, d_out, 2048, flag, 0, 1);
    } else {
        // legacy 24MB path
        unsigned short* kbuf = (unsigned short*)(ws + 1024);
        unsigned short* vbuf = (unsigned short*)(ws + 1024 + (4u << 20));
        unsigned short* abuf = (unsigned short*)(ws + 1024 + (8u << 20));
        unsigned short* qbuf = (unsigned short*)d_out;
        gemm_bt<<<dim3(M_ROWS / 64, D_MODEL / 64), blk, 0, stream>>>(hidden, Wq, qbuf, D_MODEL, flag, 1, 1, 0);
        gemm_bt<<<dim3(M_ROWS / 64, (NKVH * HEAD_DIM) / 64), blk, 0, stream>>>(hidden, Wk, kbuf, NKVH * HEAD_DIM, flag, 1, 1, 0);
        gemm_bt<<<dim3(M_ROWS / 64, (NKVH * HEAD_DIM) / 64), blk, 0, stream>>>(hidden, Wv, vbuf, NKVH * HEAD_DIM, flag, 1, 0, 0);
        attn_kernel<<<dim3(2 * NHEAD * (S_LEN / 64)), blk, 0, stream>>>(qbuf, kbuf, vbuf, abuf, 512);
        gemm_bt<<<dim3(M_ROWS / 64, D_MODEL / 64), blk, 0, stream>>>(abuf, Wo, d_out, D_MODEL, flag, 0, 0, 1);
    }
}

// Round 7
// 420.979 us; speedup vs baseline: 4.4795x; 1.0170x over previous
//
#include <hip/hip_runtime.h>

// FlashAttentionWrapper: B=2, S=2048, D=2048, NH=32, HD=64, NKV=8, NREP=4,
// causal, RoPE theta=1e4. Input dtype (bf16/f32) self-detected per block.
// New-path workspace (64MB+1KB+512KB):
//   [1KB pad][kvbuf 4096x1024 8MB][abuf 4096x2048 16MB]
//   [hbuf 16MB][wqb 8MB][wkvb 4MB][wob 8MB][vtbuf 2x512x2048 4MB]
//   [ropetab 2048x32 float2 512KB]
// wqb+wkvb are CONTIGUOUS => one [3072,2048] QKV weight matrix (fused GEMM).
// Q-projection result lives in d_out (dead before O-proj overwrites it).
// Fallback path (ws too small): original direct-load kernels, 24MB+1KB.
//
// Round-5 lesson: hand-written v_cvt_pk_bf16_f32 asm mis-packed (absmax 3.6).
// Round-7: f2bf uses the COMPILER's native __bf16 cast (HW RNE, same bits as
// the old manual RNE) — no inline asm.

#define S_LEN 2048
#define D_MODEL 2048
#define NHEAD 32
#define HEAD_DIM 64
#define NKVH 8
#define M_ROWS 4096   // B*S
#define KVW (NKVH * HEAD_DIM)   // 512

typedef __attribute__((ext_vector_type(4))) float f32x4;
typedef __attribute__((ext_vector_type(8))) short bf16x8;

#define MFMA16(a, b, c) __builtin_amdgcn_mfma_f32_16x16x32_bf16((a), (b), (c), 0, 0, 0)

// async global->LDS, 16B per lane; LDS dest is wave-uniform base + lane*16
#define GLOAD_LDS16(g, l)                                                     \
    __builtin_amdgcn_global_load_lds(                                         \
        (const __attribute__((address_space(1))) void*)(g),                   \
        (__attribute__((address_space(3))) void*)(l), 16, 0, 0)

// f32 -> bf16 RNE via native cast (compiler emits v_cvt_pk_bf16_f32; bitwise
// identical to the manual (x + 0x7fff + lsb) >> 16 RNE).
static __device__ __forceinline__ unsigned short f2bf(float f) {
    union { __bf16 b; unsigned short u; } v;
    v.b = (__bf16)f;
    return v.u;
}

static __device__ __forceinline__ float fexp2(float x) {
#if __has_builtin(__builtin_amdgcn_exp2f)
    return __builtin_amdgcn_exp2f(x);
#else
    return exp2f(x);
#endif
}

// ---------------------------------------------------------------------------
// Per-block dtype self-detection: f32 data read as uint16 shows impossible
// bf16 exponents at even indices. ~256 L2-hit loads + 2 barriers per block.
// Must be called uniformly by all 256 threads of the block.
// ---------------------------------------------------------------------------
static __device__ bool detect_f32_block(const unsigned short* __restrict__ h) {
    __shared__ int dcnt;
    if (threadIdx.x == 0) dcnt = 0;
    __syncthreads();
    const unsigned short v = h[2 * (threadIdx.x & 255)];
    const int e = (v >> 7) & 0xFF;
    if (threadIdx.x < 256 && e >= 0x8D) atomicAdd(&dcnt, 1);
    __syncthreads();
    return dcnt >= 8;
}

static __device__ __forceinline__ bf16x8 load_frag(bool f32p, const void* p, size_t off) {
    if (f32p) {
        const float* fp = (const float*)p + off;
        f32x4 x = *reinterpret_cast<const f32x4*>(fp);
        f32x4 y = *reinterpret_cast<const f32x4*>(fp + 4);
        bf16x8 r;
        r[0] = (short)f2bf(x[0]); r[1] = (short)f2bf(x[1]);
        r[2] = (short)f2bf(x[2]); r[3] = (short)f2bf(x[3]);
        r[4] = (short)f2bf(y[0]); r[5] = (short)f2bf(y[1]);
        r[6] = (short)f2bf(y[2]); r[7] = (short)f2bf(y[3]);
        return r;
    }
    return *reinterpret_cast<const bf16x8*>((const unsigned short*)p + off);
}

// ---------------------------------------------------------------------------
// RoPE cos/sin table init: tab[s*32+dd] = (cos, sin) of s * 10000^(-dd/32).
// Same exp2f/sincosf as the previous in-epilogue computation -> same bits.
// ---------------------------------------------------------------------------
__global__ __launch_bounds__(256) void rope_init(float2* __restrict__ tab) {
    const int i = blockIdx.x * 256 + threadIdx.x;   // < 2048*32
    const int s = i >> 5, dd = i & 31;
    const float inv = exp2f(-(float)dd * 0.4152410118609203f);
    const float th = (float)s * inv;
    float sn, cs;
    sincosf(th, &sn, &cs);
    tab[i] = make_float2(cs, sn);
}

// ---------------------------------------------------------------------------
// Fused one-time f32->bf16 conversion (or bf16 copy) of all 5 operands.
// ---------------------------------------------------------------------------
__global__ __launch_bounds__(256) void cvt_all(const void* __restrict__ h,
                                               const void* __restrict__ wq,
                                               const void* __restrict__ wk,
                                               const void* __restrict__ wv,
                                               const void* __restrict__ wo,
                                               unsigned short* __restrict__ hbuf,
                                               unsigned short* __restrict__ wqb,
                                               unsigned short* __restrict__ wkvb,
                                               unsigned short* __restrict__ wob) {
    const bool f32p = detect_f32_block((const unsigned short*)h);
    const int e0 = 1048576;            // hidden 4096x2048
    const int e1 = e0 + 524288;        // Wq 2048x2048
    const int e2 = e1 + 131072;        // Wk 512x2048
    const int e3 = e2 + 131072;        // Wv 512x2048
    const int e4 = e3 + 524288;        // Wo 2048x2048
    int i = blockIdx.x * 256 + threadIdx.x;
    const int stride = gridDim.x * 256;
    for (; i < e4; i += stride) {
        const void* s;
        unsigned short* d;
        size_t off;
        if (i < e0)      { s = h;  d = hbuf; off = (size_t)i; }
        else if (i < e1) { s = wq; d = wqb;  off = (size_t)(i - e0); }
        else if (i < e2) { s = wk; d = wkvb; off = (size_t)(i - e1); }
        else if (i < e3) { s = wv; d = wkvb + (size_t)512 * 2048; off = (size_t)(i - e2); }
        else             { s = wo; d = wob;  off = (size_t)(i - e3); }
        bf16x8 v = load_frag(f32p, s, off * 8);
        *reinterpret_cast<bf16x8*>(d + off * 8) = v;
    }
}

// ---------------------------------------------------------------------------
// RoPE epilogue helpers. rope4_tab uses the precomputed table (new path);
// rope4 computes trig directly (legacy fallback path).
// ---------------------------------------------------------------------------
static __device__ __forceinline__ void rope4_tab(const float2* __restrict__ tab,
                                                 const float (&vals)[4], float (&outv)[4],
                                                 int m, int l16) {
    const int s = m & (S_LEN - 1);
#pragma unroll
    for (int nt = 0; nt < 4; ++nt) {
        const int d = nt * 16 + l16;
        const float2 cs = tab[s * 32 + (d & 31)];
        const float part = vals[nt ^ 2];
        const float rot = (nt < 2) ? -part : part;  // d<32: -x2 ; d>=32: +x1
        outv[nt] = vals[nt] * cs.x + rot * cs.y;
    }
}

static __device__ __forceinline__ void rope4(const float (&vals)[4], float (&outv)[4],
                                             int m, int l16) {
    const float sf = (float)(m & (S_LEN - 1));
#pragma unroll
    for (int nt = 0; nt < 4; ++nt) {
        const int d = nt * 16 + l16;
        const float inv = exp2f(-(float)(d & 31) * 0.4152410118609203f);
        const float th = sf * inv;
        float sn, cs;
        sincosf(th, &sn, &cs);
        const float part = vals[nt ^ 2];
        const float rot = (nt < 2) ? -part : part;
        outv[nt] = vals[nt] * cs + rot * sn;
    }
}

// ---------------------------------------------------------------------------
// Fused QKV GEMM (m97 structure): A[4096,2048] @ Wqkv[3072,2048]^T, all bf16.
// 128x128 tile, BK=32, 4 waves 2x2, global_load_lds width=16. Epilogue routes
// each wave's head-aligned 64-col span: cols<2048 -> Q (d_out, stride 2048,
// RoPE); 2048..2559 -> K half of kvbuf (stride 1024, RoPE); >=2560 -> V half
// (no RoPE). RoPE via table.
// ---------------------------------------------------------------------------
__global__ __launch_bounds__(256) void gemm_qkv_lds(const unsigned short* __restrict__ A,
                                                    const unsigned short* __restrict__ W,
                                                    unsigned short* __restrict__ Qo,
                                                    unsigned short* __restrict__ KVo,
                                                    const float2* __restrict__ ropetab) {
    __shared__ unsigned short lds_a[128 * 32];   // 8KB
    __shared__ unsigned short lds_b[128 * 32];   // 8KB

    const int wave = threadIdx.x >> 6;
    const int lane = threadIdx.x & 63;
    const int l16  = lane & 15;
    const int quad = lane >> 4;
    const int wm   = wave >> 1;
    const int wn   = wave & 1;

    const int m0 = blockIdx.x * 128;
    const int n0 = blockIdx.y * 128;

    const int srow = lane >> 2;
    const int scol = (lane & 3) * 8;
    const unsigned short* ag[2];
    const unsigned short* wg[2];
#pragma unroll
    for (int i = 0; i < 2; ++i) {
        const int c = wave * 2 + i;
        ag[i] = A + (size_t)(m0 + c * 16 + srow) * D_MODEL + scol;
        wg[i] = W + (size_t)(n0 + c * 16 + srow) * D_MODEL + scol;
    }

    f32x4 acc[4][4];
#pragma unroll
    for (int i = 0; i < 4; ++i)
#pragma unroll
        for (int j = 0; j < 4; ++j) acc[i][j] = (f32x4){0.f, 0.f, 0.f, 0.f};

    for (int k0 = 0; k0 < D_MODEL; k0 += 32) {
#pragma unroll
        for (int i = 0; i < 2; ++i) {
            const int c = wave * 2 + i;
            GLOAD_LDS16(ag[i] + k0, &lds_a[c * 512]);
            GLOAD_LDS16(wg[i] + k0, &lds_b[c * 512]);
        }
        __syncthreads();

        bf16x8 af[4], bfm[4];
#pragma unroll
        for (int t = 0; t < 4; ++t) {
            af[t]  = *reinterpret_cast<const bf16x8*>(&lds_a[(wm * 64 + t * 16 + l16) * 32 + quad * 8]);
            bfm[t] = *reinterpret_cast<const bf16x8*>(&lds_b[(wn * 64 + t * 16 + l16) * 32 + quad * 8]);
        }
#pragma unroll
        for (int mt = 0; mt < 4; ++mt)
#pragma unroll
            for (int nt = 0; nt < 4; ++nt)
                acc[mt][nt] = MFMA16(af[mt], bfm[nt], acc[mt][nt]);
        __syncthreads();
    }

    const int ncol0 = n0 + wn * 64;                 // wave-uniform, head-aligned
    const bool do_rope = (ncol0 < 2048 + KVW);      // Q and K regions
    unsigned short* dst;
    int cstride, c0;
    if (ncol0 < 2048) { dst = Qo;  cstride = 2048; c0 = ncol0; }
    else              { dst = KVo; cstride = 1024; c0 = ncol0 - 2048; }

#pragma unroll
    for (int mt = 0; mt < 4; ++mt) {
#pragma unroll
        for (int r = 0; r < 4; ++r) {
            const int m = m0 + wm * 64 + mt * 16 + quad * 4 + r;
            float vals[4];
#pragma unroll
            for (int nt = 0; nt < 4; ++nt) vals[nt] = acc[mt][nt][r];
            float outv[4];
            if (do_rope) {
                rope4_tab(ropetab, vals, outv, m, l16);
            } else {
#pragma unroll
                for (int nt = 0; nt < 4; ++nt) outv[nt] = vals[nt];
            }
            unsigned short* cp = dst + (size_t)m * cstride + c0;
#pragma unroll
            for (int nt = 0; nt < 4; ++nt) cp[nt * 16 + l16] = f2bf(outv[nt]);
        }
    }
}

// ---------------------------------------------------------------------------
// LDS-staged GEMM (m97 structure): C[M,N] = A[M,2048] @ W[N,2048]^T, all bf16.
// Used for the O-projection (rope=0). finalout!=0 && input-is-f32 -> f32 out.
// hdet = original hidden buffer for dtype self-detection.
// ---------------------------------------------------------------------------
__global__ __launch_bounds__(256) void gemm_bt_lds(const unsigned short* __restrict__ A,
                                                   const unsigned short* __restrict__ W,
                                                   void* __restrict__ Cp, int N,
                                                   const unsigned short* __restrict__ hdet,
                                                   int rope, int finalout) {
    __shared__ unsigned short lds_a[128 * 32];
    __shared__ unsigned short lds_b[128 * 32];

    bool of32 = false;
    if (finalout) of32 = detect_f32_block(hdet);

    const int wave = threadIdx.x >> 6;
    const int lane = threadIdx.x & 63;
    const int l16  = lane & 15;
    const int quad = lane >> 4;
    const int wm   = wave >> 1;
    const int wn   = wave & 1;

    const int m0 = blockIdx.x * 128;
    const int n0 = blockIdx.y * 128;

    const int srow = lane >> 2;
    const int scol = (lane & 3) * 8;
    const unsigned short* ag[2];
    const unsigned short* wg[2];
#pragma unroll
    for (int i = 0; i < 2; ++i) {
        const int c = wave * 2 + i;
        ag[i] = A + (size_t)(m0 + c * 16 + srow) * D_MODEL + scol;
        wg[i] = W + (size_t)(n0 + c * 16 + srow) * D_MODEL + scol;
    }

    f32x4 acc[4][4];
#pragma unroll
    for (int i = 0; i < 4; ++i)
#pragma unroll
        for (int j = 0; j < 4; ++j) acc[i][j] = (f32x4){0.f, 0.f, 0.f, 0.f};

    for (int k0 = 0; k0 < D_MODEL; k0 += 32) {
#pragma unroll
        for (int i = 0; i < 2; ++i) {
            const int c = wave * 2 + i;
            GLOAD_LDS16(ag[i] + k0, &lds_a[c * 512]);
            GLOAD_LDS16(wg[i] + k0, &lds_b[c * 512]);
        }
        __syncthreads();

        bf16x8 af[4], bfm[4];
#pragma unroll
        for (int t = 0; t < 4; ++t) {
            af[t]  = *reinterpret_cast<const bf16x8*>(&lds_a[(wm * 64 + t * 16 + l16) * 32 + quad * 8]);
            bfm[t] = *reinterpret_cast<const bf16x8*>(&lds_b[(wn * 64 + t * 16 + l16) * 32 + quad * 8]);
        }
#pragma unroll
        for (int mt = 0; mt < 4; ++mt)
#pragma unroll
            for (int nt = 0; nt < 4; ++nt)
                acc[mt][nt] = MFMA16(af[mt], bfm[nt], acc[mt][nt]);
        __syncthreads();
    }

    const bool do_rope = (rope != 0);
    const int ncol0 = n0 + wn * 64;

#pragma unroll
    for (int mt = 0; mt < 4; ++mt) {
#pragma unroll
        for (int r = 0; r < 4; ++r) {
            const int m = m0 + wm * 64 + mt * 16 + quad * 4 + r;
            float vals[4];
#pragma unroll
            for (int nt = 0; nt < 4; ++nt) vals[nt] = acc[mt][nt][r];
            float outv[4];
            if (do_rope) {
                rope4(vals, outv, m, l16);
            } else {
#pragma unroll
                for (int nt = 0; nt < 4; ++nt) outv[nt] = vals[nt];
            }
            const size_t crow = (size_t)m * N + ncol0;
            if (of32) {
                float* cp = (float*)Cp + crow;
#pragma unroll
                for (int nt = 0; nt < 4; ++nt) cp[nt * 16 + l16] = outv[nt];
            } else {
                unsigned short* cp = (unsigned short*)Cp + crow;
#pragma unroll
                for (int nt = 0; nt < 4; ++nt) cp[nt * 16 + l16] = f2bf(outv[nt]);
            }
        }
    }
}

// ---------------------------------------------------------------------------
// V transpose: Vsrc = kvbuf V-half [B*S rows, stride 1024] cols 0..511
//   -> Vt[b][c][s] ([B][512][S]).  64x64 LDS tiles, fully coalesced.
// ---------------------------------------------------------------------------
__global__ __launch_bounds__(256) void transpose_v(const unsigned short* __restrict__ Vsrc,
                                                   unsigned short* __restrict__ Vt) {
    __shared__ unsigned short t[64][72];
    const int bid = blockIdx.x;
    const int ct = bid & 7;
    const int st = (bid >> 3) & 31;
    const int b  = bid >> 8;
    const unsigned short* src = Vsrc + ((size_t)b * S_LEN + st * 64) * 1024 + ct * 64;
    unsigned short* dst = Vt + ((size_t)b * KVW + ct * 64) * S_LEN + st * 64;
    const int r0 = threadIdx.x >> 3;
    const int c0 = (threadIdx.x & 7) * 8;
#pragma unroll
    for (int h = 0; h < 2; ++h) {
        bf16x8 v = *reinterpret_cast<const bf16x8*>(src + (size_t)(r0 + h * 32) * 1024 + c0);
        *reinterpret_cast<bf16x8*>(&t[r0 + h * 32][c0]) = v;
    }
    __syncthreads();
#pragma unroll
    for (int h = 0; h < 2; ++h) {
        const int cr = r0 + h * 32;
        bf16x8 v;
#pragma unroll
        for (int j = 0; j < 8; ++j) v[j] = (short)t[c0 + j][cr];
        *reinterpret_cast<bf16x8*>(dst + (size_t)cr * S_LEN + c0) = v;
    }
}

// ---------------------------------------------------------------------------
// Flash attention v4 (round-4/6 verified structure): causal, GQA. 4 indep
// waves/block, 32 q-rows/wave, 64-key tiles, causal-paired q-tiles (qt,15-qt).
// Log2-domain softmax with DEFERRED max (THR=8, wave-uniform __any) and
// row-sum via MFMA (l = P @ ones). P/O stores via native bf16 cast.
// ---------------------------------------------------------------------------
struct AttnCtx {
    const unsigned short* qbase;
    const unsigned short* kbase;
    const unsigned short* vtbase;
    unsigned short* obase;
    int kvs;
    int l16, quad;
    unsigned short (*lpw)[72];   // [32][72] per-wave slice
};

#define SM_C 0.18033688011112042f   // 0.125 * log2(e)
#define SM_THR 8.0f

static __device__ __forceinline__ void attn_qtile(const AttnCtx& cx, int q0w) {
    const int l16 = cx.l16, quad = cx.quad;
    const int kvs = cx.kvs;

    bf16x8 ones;
#pragma unroll
    for (int j = 0; j < 8; ++j) ones[j] = (short)0x3F80;   // bf16 1.0

    bf16x8 aq[2][2];
#pragma unroll
    for (int m = 0; m < 2; ++m)
#pragma unroll
        for (int kh = 0; kh < 2; ++kh)
            aq[m][kh] = *reinterpret_cast<const bf16x8*>(
                cx.qbase + (size_t)(q0w + m * 16 + l16) * D_MODEL + kh * 32 + quad * 8);

    f32x4 o[2][4];
    f32x4 c_l[2];     // row-sum accumulator (l = P @ ones)
#pragma unroll
    for (int m = 0; m < 2; ++m) {
#pragma unroll
        for (int i = 0; i < 4; ++i) o[m][i] = (f32x4){0.f, 0.f, 0.f, 0.f};
        c_l[m] = (f32x4){0.f, 0.f, 0.f, 0.f};
    }
    float m2[2][4];   // running max, log2 domain
#pragma unroll
    for (int m = 0; m < 2; ++m)
#pragma unroll
        for (int r = 0; r < 4; ++r) m2[m][r] = 0.f;

    const int kv_hi = q0w + 32;   // per-wave causal bound

    bf16x8 kfa[8], kfb[8];        // K frags [t*2+kh], double-buffered

#define LOADK(DST, KK0)                                                       \
    {                                                                         \
        _Pragma("unroll")                                                     \
        for (int t = 0; t < 4; ++t) {                                         \
            const unsigned short* krow =                                      \
                cx.kbase + (size_t)((KK0) + t * 16 + l16) * kvs;              \
            DST[2 * t]     = *reinterpret_cast<const bf16x8*>(krow + quad * 8);       \
            DST[2 * t + 1] = *reinterpret_cast<const bf16x8*>(krow + 32 + quad * 8);  \
        }                                                                     \
    }

#define ATTN_BODY(CUR, NXT)                                                   \
    {                                                                         \
        f32x4 sc[2][4];                                                       \
        __builtin_amdgcn_s_setprio(1);                                        \
        _Pragma("unroll")                                                     \
        for (int t = 0; t < 4; ++t) {                                         \
            _Pragma("unroll")                                                 \
            for (int m = 0; m < 2; ++m) {                                     \
                f32x4 c = (f32x4){0.f, 0.f, 0.f, 0.f};                        \
                c = MFMA16(aq[m][0], CUR[2 * t], c);                          \
                c = MFMA16(aq[m][1], CUR[2 * t + 1], c);                      \
                sc[m][t] = c;                                                 \
            }                                                                 \
        }                                                                     \
        __builtin_amdgcn_s_setprio(0);                                        \
        if (k0 + 64 < kv_hi) LOADK(NXT, k0 + 64);                             \
        bf16x8 vf[8];                                                         \
        _Pragma("unroll")                                                     \
        for (int nt = 0; nt < 4; ++nt) {                                      \
            const unsigned short* vrow =                                      \
                cx.vtbase + (size_t)(nt * 16 + l16) * S_LEN + k0 + quad * 8;  \
            vf[2 * nt]     = *reinterpret_cast<const bf16x8*>(vrow);          \
            vf[2 * nt + 1] = *reinterpret_cast<const bf16x8*>(vrow + 32);     \
        }                                                                     \
        const bool full = (k0 + 63 <= q0w);                                   \
        float pm[2][4];                                                       \
        float dif = -3.0e38f;                                                 \
        _Pragma("unroll")                                                     \
        for (int m = 0; m < 2; ++m) {                                         \
            _Pragma("unroll")                                                 \
            for (int r = 0; r < 4; ++r) {                                     \
                const int qi = q0w + m * 16 + quad * 4 + r;                   \
                float s[4];                                                   \
                _Pragma("unroll")                                             \
                for (int t = 0; t < 4; ++t) {                                 \
                    s[t] = sc[m][t][r] * SM_C;                                \
                    if (!full && (k0 + t * 16 + l16 > qi)) s[t] = -1.0e30f;   \
                    sc[m][t][r] = s[t];                                       \
                }                                                             \
                const float p = fmaxf(fmaxf(s[0], s[1]), fmaxf(s[2], s[3])); \
                pm[m][r] = p;                                                 \
                dif = fmaxf(dif, p - m2[m][r]);                               \
            }                                                                 \
        }                                                                     \
        if (__any(dif > SM_THR)) {                                            \
            _Pragma("unroll")                                                 \
            for (int m = 0; m < 2; ++m) {                                     \
                _Pragma("unroll")                                             \
                for (int r = 0; r < 4; ++r) {                                 \
                    float mt = pm[m][r];                                      \
                    _Pragma("unroll")                                         \
                    for (int off = 1; off < 16; off <<= 1)                    \
                        mt = fmaxf(mt, __shfl_xor(mt, off, 64));              \
                    const float mn = fmaxf(m2[m][r], mt);                     \
                    const float al = fexp2(m2[m][r] - mn);                    \
                    m2[m][r] = mn;                                            \
                    _Pragma("unroll")                                         \
                    for (int nt = 0; nt < 4; ++nt) o[m][nt][r] *= al;         \
                    c_l[m][r] *= al;                                          \
                }                                                             \
            }                                                                 \
        }                                                                     \
        /* pass 2: p = 2^(s - m2), write P tile */                            \
        _Pragma("unroll")                                                     \
        for (int m = 0; m < 2; ++m) {                                         \
            _Pragma("unroll")                                                 \
            for (int r = 0; r < 4; ++r) {                                     \
                const float mb = m2[m][r];                                    \
                _Pragma("unroll")                                             \
                for (int t = 0; t < 4; ++t) {                                 \
                    const float pv = fexp2(sc[m][t][r] - mb);                 \
                    cx.lpw[m * 16 + quad * 4 + r][t * 16 + l16] = f2bf(pv);   \
                }                                                             \
            }                                                                 \
        }                                                                     \
        asm volatile("" ::: "memory");                                        \
        bf16x8 ap[2][2];                                                      \
        _Pragma("unroll")                                                     \
        for (int m = 0; m < 2; ++m)                                           \
            _Pragma("unroll")                                                 \
            for (int kh = 0; kh < 2; ++kh)                                    \
                ap[m][kh] = *reinterpret_cast<const bf16x8*>(                 \
                    &cx.lpw[m * 16 + l16][kh * 32 + quad * 8]);               \
        __builtin_amdgcn_s_setprio(1);                                        \
        _Pragma("unroll")                                                     \
        for (int nt = 0; nt < 4; ++nt)                                        \
            _Pragma("unroll")                                                 \
            for (int m = 0; m < 2; ++m) {                                     \
                o[m][nt] = MFMA16(ap[m][0], vf[2 * nt], o[m][nt]);            \
                o[m][nt] = MFMA16(ap[m][1], vf[2 * nt + 1], o[m][nt]);        \
            }                                                                 \
        _Pragma("unroll")                                                     \
        for (int m = 0; m < 2; ++m) {                                         \
            c_l[m] = MFMA16(ap[m][0], ones, c_l[m]);                          \
            c_l[m] = MFMA16(ap[m][1], ones, c_l[m]);                          \
        }                                                                     \
        __builtin_amdgcn_s_setprio(0);                                        \
    }

    LOADK(kfa, 0);
    int k0 = 0;
    for (;;) {
        ATTN_BODY(kfa, kfb);
        k0 += 64;
        if (k0 >= kv_hi) break;
        ATTN_BODY(kfb, kfa);
        k0 += 64;
        if (k0 >= kv_hi) break;
    }
#undef ATTN_BODY
#undef LOADK

#pragma unroll
    for (int m = 0; m < 2; ++m)
#pragma unroll
        for (int r = 0; r < 4; ++r) {
            const float inv_l = 1.0f / c_l[m][r];
            unsigned short* orow = cx.obase + (size_t)(q0w + m * 16 + quad * 4 + r) * D_MODEL;
#pragma unroll
            for (int nt = 0; nt < 4; ++nt)
                orow[nt * 16 + l16] = f2bf(o[m][nt][r] * inv_l);
        }
}

__global__ __launch_bounds__(256) void attn_kernel4(const unsigned short* __restrict__ Q,
                                                    const unsigned short* __restrict__ Kb,
                                                    const unsigned short* __restrict__ Vt,
                                                    unsigned short* __restrict__ O, int kvs) {
    __shared__ unsigned short lp[4][32][72];   // per-wave P (32 q x 64 k), padded

    const int wave = threadIdx.x >> 6;
    const int lane = threadIdx.x & 63;

    const int bid = blockIdx.x;
    const int p   = bid & 7;                    // pair index: q-tiles p and 15-p
    const int h   = (bid >> 3) & (NHEAD - 1);
    const int b   = bid >> 8;
    const int kvh = h >> 2;

    AttnCtx cx;
    cx.qbase  = Q + (size_t)b * S_LEN * D_MODEL + h * HEAD_DIM;
    cx.kbase  = Kb + (size_t)b * S_LEN * kvs + kvh * HEAD_DIM;
    cx.vtbase = Vt + ((size_t)b * KVW + kvh * HEAD_DIM) * S_LEN;
    cx.obase  = O + (size_t)b * S_LEN * D_MODEL + h * HEAD_DIM;
    cx.kvs    = kvs;
    cx.l16    = lane & 15;
    cx.quad   = lane >> 4;
    cx.lpw    = lp[wave];

    attn_qtile(cx, p * 128 + wave * 32);                 // light tile
    attn_qtile(cx, (15 - p) * 128 + wave * 32);          // heavy tile
}

// ---------------------------------------------------------------------------
// Legacy direct-load GEMM + attention (fallback path only).
// ---------------------------------------------------------------------------
__global__ __launch_bounds__(256) void gemm_bt(const void* __restrict__ Ap,
                                               const void* __restrict__ Wp,
                                               void* __restrict__ Cp, int N,
                                               const unsigned short* __restrict__ hdet,
                                               int a_input, int rope, int finalout) {
    const bool isf32 = detect_f32_block(hdet);
    const bool af32 = isf32 && (a_input != 0);
    const bool wf32 = isf32;
    const bool of32 = isf32 && (finalout != 0);

    const int wave = threadIdx.x >> 6;
    const int lane = threadIdx.x & 63;
    const int l16  = lane & 15;
    const int quad = lane >> 4;
    const int m0 = blockIdx.x * 64 + wave * 16;
    const int n0 = blockIdx.y * 64;

    f32x4 acc[4];
#pragma unroll
    for (int i = 0; i < 4; ++i) acc[i] = (f32x4){0.f, 0.f, 0.f, 0.f};

    const size_t aoff = (size_t)(m0 + l16) * D_MODEL + quad * 8;
    size_t woff[4];
#pragma unroll
    for (int nt = 0; nt < 4; ++nt)
        woff[nt] = (size_t)(n0 + nt * 16 + l16) * D_MODEL + quad * 8;

    for (int k0 = 0; k0 < D_MODEL; k0 += 32) {
        bf16x8 a = load_frag(af32, Ap, aoff + k0);
#pragma unroll
        for (int nt = 0; nt < 4; ++nt) {
            bf16x8 b = load_frag(wf32, Wp, woff[nt] + k0);
            acc[nt] = MFMA16(a, b, acc[nt]);
        }
    }

#pragma unroll
    for (int r = 0; r < 4; ++r) {
        const int m = m0 + quad * 4 + r;
        float vals[4];
#pragma unroll
        for (int nt = 0; nt < 4; ++nt) vals[nt] = acc[nt][r];
        float outv[4];
        if (rope) {
            rope4(vals, outv, m, l16);
        } else {
#pragma unroll
            for (int nt = 0; nt < 4; ++nt) outv[nt] = vals[nt];
        }
        const size_t crow = (size_t)m * N + n0;
        if (of32) {
            float* cp = (float*)Cp + crow;
#pragma unroll
            for (int nt = 0; nt < 4; ++nt) cp[nt * 16 + l16] = outv[nt];
        } else {
            unsigned short* cp = (unsigned short*)Cp + crow;
#pragma unroll
            for (int nt = 0; nt < 4; ++nt) cp[nt * 16 + l16] = f2bf(outv[nt]);
        }
    }
}

__global__ __launch_bounds__(256) void attn_kernel(const unsigned short* __restrict__ Q,
                                                   const unsigned short* __restrict__ Kb,
                                                   const unsigned short* __restrict__ Vb,
                                                   unsigned short* __restrict__ O, int kvs) {
    __shared__ unsigned short lp[4][16][32];

    const int wave = threadIdx.x >> 6;
    const int lane = threadIdx.x & 63;
    const int l16  = lane & 15;
    const int quad = lane >> 4;

    const int bid = blockIdx.x;
    const int qb  = bid & 31;
    const int h   = (bid >> 5) & 31;
    const int b   = bid >> 10;
    const int kvh = h >> 2;
    const int q0  = qb * 64 + wave * 16;

    const unsigned short* qbase = Q + (size_t)b * S_LEN * D_MODEL + h * HEAD_DIM;
    const unsigned short* kbase = Kb + (size_t)b * S_LEN * kvs + kvh * HEAD_DIM;
    const unsigned short* vbase = Vb + (size_t)b * S_LEN * kvs + kvh * HEAD_DIM;

    bf16x8 aq0 = *reinterpret_cast<const bf16x8*>(qbase + (size_t)(q0 + l16) * D_MODEL + quad * 8);
    bf16x8 aq1 = *reinterpret_cast<const bf16x8*>(qbase + (size_t)(q0 + l16) * D_MODEL + 32 + quad * 8);

    f32x4 o[4];
#pragma unroll
    for (int i = 0; i < 4; ++i) o[i] = (f32x4){0.f, 0.f, 0.f, 0.f};
    float mrow[4], lrow[4];
#pragma unroll
    for (int r = 0; r < 4; ++r) { mrow[r] = -3.0e38f; lrow[r] = 0.f; }

    const int kv_hi = qb * 64 + 64;
    for (int k0 = 0; k0 < kv_hi; k0 += 32) {
        f32x4 sc[2];
#pragma unroll
        for (int t = 0; t < 2; ++t) {
            const unsigned short* krow = kbase + (size_t)(k0 + t * 16 + l16) * kvs;
            bf16x8 b0 = *reinterpret_cast<const bf16x8*>(krow + quad * 8);
            bf16x8 b1 = *reinterpret_cast<const bf16x8*>(krow + 32 + quad * 8);
            f32x4 c = (f32x4){0.f, 0.f, 0.f, 0.f};
            c = MFMA16(aq0, b0, c);
            c = MFMA16(aq1, b1, c);
            sc[t] = c;
        }

        float alpha[4], p0v[4], p1v[4];
#pragma unroll
        for (int r = 0; r < 4; ++r) {
            const int qi = q0 + quad * 4 + r;
            float s0 = sc[0][r] * 0.125f;
            float s1 = sc[1][r] * 0.125f;
            if (k0 + l16 > qi)       s0 = -1.0e30f;
            if (k0 + 16 + l16 > qi)  s1 = -1.0e30f;
            float mt = fmaxf(s0, s1);
#pragma unroll
            for (int off = 1; off < 16; off <<= 1) mt = fmaxf(mt, __shfl_xor(mt, off, 64));
            const float mn = fmaxf(mrow[r], mt);
            const float al = __expf(mrow[r] - mn);
            const float p0 = __expf(s0 - mn);
            const float p1 = __expf(s1 - mn);
            float rs = p0 + p1;
#pragma unroll
            for (int off = 1; off < 16; off <<= 1) rs += __shfl_xor(rs, off, 64);
            lrow[r] = lrow[r] * al + rs;
            mrow[r] = mn;
            alpha[r] = al;
            p0v[r] = p0; p1v[r] = p1;
        }
#pragma unroll
        for (int nt = 0; nt < 4; ++nt)
#pragma unroll
            for (int r = 0; r < 4; ++r) o[nt][r] *= alpha[r];

        __syncthreads();
#pragma unroll
        for (int r = 0; r < 4; ++r) {
            lp[wave][quad * 4 + r][l16]      = f2bf(p0v[r]);
            lp[wave][quad * 4 + r][16 + l16] = f2bf(p1v[r]);
        }
        __syncthreads();
        bf16x8 ap = *reinterpret_cast<const bf16x8*>(&lp[wave][l16][quad * 8]);

#pragma unroll
        for (int nt = 0; nt < 4; ++nt) {
            const unsigned short* vcol = vbase + nt * 16 + l16 + (size_t)(k0 + quad * 8) * kvs;
            bf16x8 bv;
#pragma unroll
            for (int j = 0; j < 8; ++j) bv[j] = (short)vcol[(size_t)j * kvs];
            o[nt] = MFMA16(ap, bv, o[nt]);
        }
    }

    unsigned short* obase = O + (size_t)b * S_LEN * D_MODEL + h * HEAD_DIM;
#pragma unroll
    for (int r = 0; r < 4; ++r) {
        const float inv_l = 1.0f / lrow[r];
        unsigned short* orow = obase + (size_t)(q0 + quad * 4 + r) * D_MODEL;
#pragma unroll
        for (int nt = 0; nt < 4; ++nt)
            orow[nt * 16 + l16] = f2bf(o[nt][r] * inv_l);
    }
}

extern "C" void kernel_launch(void* const* d_in, const int* in_sizes, int n_in,
                              void* d_out, int out_size, void* d_ws, size_t ws_size,
                              hipStream_t stream) {
    const void* hidden = d_in[0];
    const void* Wq = d_in[1];
    const void* Wk = d_in[2];
    const void* Wv = d_in[3];
    const void* Wo = d_in[4];
    // d_in[5] = attention_mask: pure causal -1e9 -> implemented directly.

    char* ws = (char*)d_ws;
    dim3 blk(256);

    // kv 8MB + abuf 16MB + hbuf 16MB + wq 8MB + wkv 4MB + wo 8MB + vt 4MB + tab 512KB
    const size_t NEED = 1024 + ((size_t)64 << 20) + (512u << 10);
    if (ws_size >= NEED) {
        unsigned short* kvbuf = (unsigned short*)(ws + 1024);      // [4096,1024]: K cols 0-511, V cols 512-1023
        unsigned short* abuf  = kvbuf + (size_t)4096 * 1024;       // [4096,2048]
        unsigned short* hbuf  = abuf + (size_t)4096 * 2048;        // hidden bf16
        unsigned short* wqb   = hbuf + (size_t)4096 * 2048;        // [2048,2048]  } contiguous =
        unsigned short* wkvb  = wqb + (size_t)2048 * 2048;         // [1024,2048]  } Wqkv [3072,2048]
        unsigned short* wob   = wkvb + (size_t)1024 * 2048;        // [2048,2048]
        unsigned short* vtbuf = wob + (size_t)2048 * 2048;         // [2,512,2048] V^T
        float2* ropetab       = (float2*)(vtbuf + (size_t)2 * 512 * 2048);  // [2048][32]
        unsigned short* qbuf  = (unsigned short*)d_out;            // Q bf16 lives in d_out

        rope_init<<<dim3(256), blk, 0, stream>>>(ropetab);
        cvt_all<<<dim3(2048), blk, 0, stream>>>(hidden, Wq, Wk, Wv, Wo,
                                                hbuf, wqb, wkvb, wob);

        gemm_qkv_lds<<<dim3(32, 24), blk, 0, stream>>>(hbuf, wqb, qbuf, kvbuf, ropetab);
        transpose_v<<<dim3(512), blk, 0, stream>>>(kvbuf + 512, vtbuf);
        attn_kernel4<<<dim3(2 * NHEAD * (S_LEN / 256)), blk, 0, stream>>>(qbuf, kvbuf, vtbuf, abuf, 1024);
        gemm_bt_lds<<<dim3(32, 16), blk, 0, stream>>>(abuf, wob, d_out, 2048,
                                                      (const unsigned short*)hidden, 0, 1);
    } else {
        // legacy 24MB path
        unsigned short* kbuf = (unsigned short*)(ws + 1024);
        unsigned short* vbuf = (unsigned short*)(ws + 1024 + (4u << 20));
        unsigned short* abuf = (unsigned short*)(ws + 1024 + (8u << 20));
        unsigned short* qbuf = (unsigned short*)d_out;
        const unsigned short* hdet = (const unsigned short*)hidden;
        gemm_bt<<<dim3(M_ROWS / 64, D_MODEL / 64), blk, 0, stream>>>(hidden, Wq, qbuf, D_MODEL, hdet, 1, 1, 0);
        gemm_bt<<<dim3(M_ROWS / 64, (NKVH * HEAD_DIM) / 64), blk, 0, stream>>>(hidden, Wk, kbuf, NKVH * HEAD_DIM, hdet, 1, 1, 0);
        gemm_bt<<<dim3(M_ROWS / 64, (NKVH * HEAD_DIM) / 64), blk, 0, stream>>>(hidden, Wv, vbuf, NKVH * HEAD_DIM, hdet, 1, 0, 0);
        attn_kernel<<<dim3(2 * NHEAD * (S_LEN / 64)), blk, 0, stream>>>(qbuf, kbuf, vbuf, abuf, 512);
        gemm_bt<<<dim3(M_ROWS / 64, D_MODEL / 64), blk, 0, stream>>>(abuf, Wo, d_out, D_MODEL, hdet, 0, 0, 1);
    }
}